// Round 4
// baseline (192.467 us; speedup 1.0000x reference)
//
#include <hip/hip_runtime.h>
#include <math.h>

// q,k,v: [B=2, H=16, N=2048, Dh=64] fp32.  BH = 32 independent heads.
#define BH 32
#define NN 2048
#define DD 64
#define BHNN (BH * NN)        // 65536 rows total
#define QK ((size_t)BH * NN * DD)  // 4,194,304 elems per tensor

// 8 * log2(e): logits produced in base-2 domain so all softmax exps are a bare
// v_exp_f32 (exp2). Softmax is invariant to the base change.
#define QSCALE 11.5415603f

// Precision scheme (R11): fp16 q-hi/lo x fp16 k-single, 2 MFMAs per k-slice.
//
// R14 register ledger (gfx950 UNIFIED VGPR+AGPR file -- AGPRs count!):
//   Measured history: acc[4]+reg-prefetch demands ~175 unified:
//     (256,2) cap 256: clean, 2 blk/CU, stats 57.6us (R11)
//     (256,4) cap 128: heavy spill, WRITE 23.6MB (R12)
//     (256,3) cap 170: mild spill 4.9MB AND still 2 blk/CU (R13)
//   => shrink demand, don't squeeze it. global_load_lds staging removes the
//   rh[4] prefetch (16 regs) + all staging VALU: demand ~145 <= 170.
//
// K layout (R14): khi holds 16KB tiles [bh][tile][128 rows][64 cols] with an
// intra-row swizzle: 8-elem granule j stored at j ^ (row&7). global_load_lds
// then stages the image LINEARLY (lane*16B) and the ds_read applies the same
// XOR -> lanes 0..7 hit 8 disjoint 16B slots = all 32 banks, zero conflicts
// (rule: swizzle BOTH sides or neither; LDS dest of global_load_lds is
// always linear).
typedef __attribute__((ext_vector_type(8)))  _Float16 halfx8;
typedef __attribute__((ext_vector_type(4)))  _Float16 halfx4;
typedef __attribute__((ext_vector_type(16))) float    floatx16;

__device__ inline float fexp2(float x) { return __builtin_amdgcn_exp2f(x); }

// C/D row for accumulator register r (0..15) given half = lane>>5 (verified R2).
__device__ inline int rowmap(int r, int half) {
    return (r & 3) + 8 * (r >> 2) + 4 * half;
}

// ---------------------------------------------------------------------------
// Pre-convert: q -> fp16 hi/lo (QSCALE folded), k -> fp16 single, swizzled.
// khi element for (row r, col c): (e & ~63) + (((c>>3) ^ (r&7))<<3) + (c&7).
// Per float4-thread: 4 consecutive cols share a granule -> single halfx4 write.
// ---------------------------------------------------------------------------
__global__ __launch_bounds__(256) void convert_kernel(const float4* __restrict__ q,
                                                      const float4* __restrict__ k,
                                                      _Float16* __restrict__ qhi,
                                                      _Float16* __restrict__ qlo,
                                                      _Float16* __restrict__ khi) {
    size_t gid = (size_t)blockIdx.x * 256 + threadIdx.x;  // float4 index, QK/4 total
    float4 qa = q[gid];
    float4 ka = k[gid];
    float qf[4] = {qa.x, qa.y, qa.z, qa.w};
    float kf[4] = {ka.x, ka.y, ka.z, ka.w};
    halfx4 h, l, kh;
#pragma unroll
    for (int i = 0; i < 4; ++i) {
        float f = qf[i] * QSCALE;
        _Float16 hh = (_Float16)f;           // RN
        h[i] = hh;
        l[i] = (_Float16)(f - (float)hh);    // residual, RN
        kh[i] = (_Float16)kf[i];
    }
    *(halfx4*)&qhi[gid * 4] = h;
    *(halfx4*)&qlo[gid * 4] = l;
    // swizzled K: row = (gid>>4)&127; granule j = (gid>>1)&7; sub = (gid&1)*4
    size_t rowbase = (gid * 4) & ~(size_t)63;
    int j = (int)((gid >> 1) & 7) ^ (int)((gid >> 4) & 7);
    *(halfx4*)&khi[rowbase + (size_t)(j << 3) + ((gid & 1) << 2)] = kh;
}

// ---------------------------------------------------------------------------
// Async stage: one 16KB K-tile image -> LDS, linear copy, no VGPR round-trip.
// LDS dest = wave-uniform base + lane*16 (HW rule); global src per-lane.
// Tracked by vmcnt; __syncthreads() drains it.
// ---------------------------------------------------------------------------
__device__ inline void stage_tile_async(const _Float16* __restrict__ gtile,
                                        _Float16* lds, int wave, int lane) {
#pragma unroll
    for (int i = 0; i < 4; ++i) {
        const char* gp = (const char*)gtile + wave * 4096 + i * 1024 + lane * 16;
        char* lp = (char*)lds + wave * 4096 + i * 1024;   // wave-uniform
        __builtin_amdgcn_global_load_lds(
            (const __attribute__((address_space(1))) unsigned int*)gp,
            (__attribute__((address_space(3))) unsigned int*)lp, 16, 0, 0);
    }
}

// ---- A-operand fragments: lane holds A[m=lane&31][k=(lane>>5)*8+j] ----------
__device__ inline void load_a(const _Float16* __restrict__ qhi_row,
                              const _Float16* __restrict__ qlo_row,
                              int half, halfx8 ah[4], halfx8 al[4]) {
#pragma unroll
    for (int ks = 0; ks < 4; ++ks) {
        ah[ks] = *(const halfx8*)&qhi_row[ks * 16 + half * 8];
        al[ks] = *(const halfx8*)&qlo_row[ks * 16 + half * 8];
    }
}

// ---------------------------------------------------------------------------
// Phase 1: per-row softmax stats (base-2), PARTIAL over an m-half.
// 1D grid 1024: idx = (bh + 32*ms) + 64*nblk -> blocks sharing a K-half are
// congruent mod 8 => same XCD (L2 locality). Lazy per-lane online stats.
// Double-buffered direct-to-LDS staging: issue tile t+1, compute tile t,
// __syncthreads (drains vmcnt(0) + barrier) -- guide's minimum 2-phase.
// ---------------------------------------------------------------------------
__global__ __launch_bounds__(256, 3) void stats_kernel(const _Float16* __restrict__ qhi,
                                                       const _Float16* __restrict__ qlo,
                                                       const _Float16* __restrict__ khi,
                                                       float* __restrict__ smax_p,
                                                       float* __restrict__ sden_p) {
    __shared__ _Float16 K2[2 * 128 * 64];  // 32 KB, two tile buffers
    const int g    = blockIdx.x & 63;      // bh + 32*ms
    const int bh   = g & 31;
    const int ms   = g >> 5;               // m-split: tiles [ms*8, ms*8+8)
    const int n0   = (blockIdx.x >> 6) * 128;
    const int tid  = threadIdx.x;
    const int wave = tid >> 6, lane = tid & 63;
    const int half = lane >> 5, l31 = lane & 31;
    const int xr   = l31 & 7;              // row&7 for swizzled reads (t*32 == 0 mod 8)
    const size_t base = (size_t)bh * NN * DD;

    const _Float16* khi_b = khi + base;
    stage_tile_async(khi_b + (size_t)(ms * 8) * 8192, K2, wave, lane);

    // A fragments: fixed rows for the whole kernel.
    halfx8 ah[4], al[4];
    {
        size_t ro = base + (size_t)(n0 + wave * 32 + l31) * DD;
        load_a(qhi + ro, qlo + ro, half, ah, al);
    }

    float m_run[16], d_run[16];
#pragma unroll
    for (int r = 0; r < 16; ++r) { m_run[r] = -INFINITY; d_run[r] = 0.f; }

    __syncthreads();                       // tile 0 landed (vmcnt drain) + barrier

    for (int mti = 0; mti < 8; ++mti) {
        const _Float16* Kc = K2 + (mti & 1) * 8192;
        if (mti < 7)                       // issue next tile BEFORE compute
            stage_tile_async(khi_b + (size_t)(ms * 8 + mti + 1) * 8192,
                             K2 + ((mti + 1) & 1) * 8192, wave, lane);

        floatx16 acc[4];
#pragma unroll
        for (int t = 0; t < 4; ++t)
#pragma unroll
            for (int e = 0; e < 16; ++e) acc[t][e] = 0.f;

#pragma unroll
        for (int t = 0; t < 4; ++t) {
            const int mr = t * 32 + l31;
            const _Float16* rowp = Kc + (size_t)mr * 64;
#pragma unroll
            for (int ks = 0; ks < 4; ++ks) {
                const int j = (ks * 2 + half) ^ xr;
                halfx8 bhf = *(const halfx8*)&rowp[j << 3];
                acc[t] = __builtin_amdgcn_mfma_f32_32x32x16_f16(ah[ks], bhf, acc[t], 0, 0, 0);
                acc[t] = __builtin_amdgcn_mfma_f32_32x32x16_f16(al[ks], bhf, acc[t], 0, 0, 0);
            }
        }

        // Lazy per-lane online stats, base-2 domain.
#pragma unroll
        for (int r = 0; r < 16; ++r) {
            float tmax = fmaxf(fmaxf(acc[0][r], acc[1][r]), fmaxf(acc[2][r], acc[3][r]));
            float m_new = fmaxf(m_run[r], tmax);
            float s = fexp2(acc[0][r] - m_new) + fexp2(acc[1][r] - m_new)
                    + fexp2(acc[2][r] - m_new) + fexp2(acc[3][r] - m_new);
            d_run[r] = d_run[r] * fexp2(m_run[r] - m_new) + s;
            m_run[r] = m_new;
        }

        if (mti < 7) __syncthreads();      // t+1 loads landed + all waves done with Kc
    }

    // Cross-lane combine within each 32-lane half (rows differ across halves).
    float* smp = smax_p + ((size_t)ms * BH + bh) * NN;
    float* sdp = sden_p + ((size_t)ms * BH + bh) * NN;
#pragma unroll
    for (int r = 0; r < 16; ++r) {
        float M = m_run[r];
#pragma unroll
        for (int off = 1; off < 32; off <<= 1)
            M = fmaxf(M, __shfl_xor(M, off));
        float dd = d_run[r] * fexp2(m_run[r] - M);
#pragma unroll
        for (int off = 1; off < 32; off <<= 1)
            dd += __shfl_xor(dd, off);
        if (l31 == 0) {
            int row = n0 + wave * 32 + rowmap(r, half);
            smp[row] = M;
            sdp[row] = dd;
        }
    }
}

// ---------------------------------------------------------------------------
// Phase 2: partial w[m] over an n-half. 1D grid 1024 with mod-8 XCD swizzle.
// Block owns 128 cols; K tile staged ONCE via global_load_lds (one-shot, the
// plain __syncthreads drain is fine). m-split combine folded into staging.
// ---------------------------------------------------------------------------
__global__ __launch_bounds__(256, 3) void wsum_kernel(const _Float16* __restrict__ qhi,
                                                      const _Float16* __restrict__ qlo,
                                                      const _Float16* __restrict__ khi,
                                                      const float* __restrict__ smax_p,
                                                      const float* __restrict__ sden_p,
                                                      float* __restrict__ wpart) {
    __shared__ _Float16 Khi[128 * 64];     // 16 KB, single tile
    __shared__ float wred[4 * 128];
    __shared__ float Ms[1024];
    __shared__ float Is[1024];
    const int g    = blockIdx.x & 63;      // bh + 32*nz
    const int bh   = g & 31;
    const int nz   = g >> 5;               // n-split: rows [nz*1024, +1024)
    const int m0   = (blockIdx.x >> 6) * 128;
    const int tid  = threadIdx.x;
    const int wave = tid >> 6, lane = tid & 63;
    const int half = lane >> 5, l31 = lane & 31;
    const int xr   = l31 & 7;
    const size_t base = (size_t)bh * NN * DD;

    stage_tile_async(khi + base + (size_t)m0 * 64, Khi, wave, lane);

    {   // combine row stats inline (4 rows/thread) while the tile streams in
        size_t roff = (size_t)bh * NN + nz * 1024 + tid * 4;
        float4 m0v = *(const float4*)&smax_p[roff];
        float4 m1v = *(const float4*)&smax_p[(size_t)BHNN + roff];
        float4 d0v = *(const float4*)&sden_p[roff];
        float4 d1v = *(const float4*)&sden_p[(size_t)BHNN + roff];
        float mm0[4] = {m0v.x, m0v.y, m0v.z, m0v.w};
        float mm1[4] = {m1v.x, m1v.y, m1v.z, m1v.w};
        float dd0[4] = {d0v.x, d0v.y, d0v.z, d0v.w};
        float dd1[4] = {d1v.x, d1v.y, d1v.z, d1v.w};
#pragma unroll
        for (int j = 0; j < 4; ++j) {
            float M = fmaxf(mm0[j], mm1[j]);
            float den = dd0[j] * fexp2(mm0[j] - M) + dd1[j] * fexp2(mm1[j] - M);
            Ms[tid * 4 + j] = M;
            Is[tid * 4 + j] = 1.0f / den;
        }
    }
    __syncthreads();                       // K tile landed + Ms/Is visible

    float wacc[4] = {0.f, 0.f, 0.f, 0.f};

#pragma unroll
    for (int it = 0; it < 8; ++it) {
        const int ls = wave + it * 4;      // local strip 0..31
        halfx8 ah[4], al[4];
        {
            size_t ro = base + (size_t)((nz * 32 + ls) * 32 + l31) * DD;
            load_a(qhi + ro, qlo + ro, half, ah, al);
        }

        floatx16 acc[4];
#pragma unroll
        for (int t = 0; t < 4; ++t)
#pragma unroll
            for (int e = 0; e < 16; ++e) acc[t][e] = 0.f;

#pragma unroll
        for (int t = 0; t < 4; ++t) {
            const int mr = t * 32 + l31;
            const _Float16* rowp = Khi + (size_t)mr * 64;
#pragma unroll
            for (int ks = 0; ks < 4; ++ks) {
                const int j = (ks * 2 + half) ^ xr;
                halfx8 bhf = *(const halfx8*)&rowp[j << 3];
                acc[t] = __builtin_amdgcn_mfma_f32_32x32x16_f16(ah[ks], bhf, acc[t], 0, 0, 0);
                acc[t] = __builtin_amdgcn_mfma_f32_32x32x16_f16(al[ks], bhf, acc[t], 0, 0, 0);
            }
        }

#pragma unroll
        for (int r = 0; r < 16; ++r) {
            const int lrow = ls * 32 + rowmap(r, half);   // broadcast LDS read
            float M   = Ms[lrow];
            float inv = Is[lrow];
#pragma unroll
            for (int t = 0; t < 4; ++t)
                wacc[t] += fexp2(acc[t][r] - M) * inv;
        }
    }

    // halves hold same cols, different rows: sum across halves, then waves.
#pragma unroll
    for (int t = 0; t < 4; ++t) wacc[t] += __shfl_xor(wacc[t], 32);
    if (half == 0) {
#pragma unroll
        for (int t = 0; t < 4; ++t) wred[wave * 128 + t * 32 + l31] = wacc[t];
    }
    __syncthreads();
    if (tid < 128) {
        float s = wred[tid] + wred[128 + tid] + wred[256 + tid] + wred[384 + tid];
        wpart[((size_t)nz * BH + bh) * NN + m0 + tid] = s;
    }
}

// ---------------------------------------------------------------------------
// Phase 3: out[b,h,m,d] = (w0[m]+w1[m]) * v[b,h,m,d]
// ---------------------------------------------------------------------------
__global__ __launch_bounds__(256) void out_kernel(const float* __restrict__ v,
                                                  const float* __restrict__ w0,
                                                  const float* __restrict__ w1,
                                                  float* __restrict__ out) {
    size_t gid = (size_t)blockIdx.x * 256 + threadIdx.x;  // float4 index
    const float4* v4 = (const float4*)v;
    float4* o4 = (float4*)out;
    float4 vv = v4[gid];
    float ww = w0[gid >> 4] + w1[gid >> 4];
    o4[gid] = make_float4(vv.x * ww, vv.y * ww, vv.z * ww, vv.w * ww);
}

extern "C" void kernel_launch(void* const* d_in, const int* in_sizes, int n_in,
                              void* d_out, int out_size, void* d_ws, size_t ws_size,
                              hipStream_t stream) {
    const float* q = (const float*)d_in[0];
    const float* k = (const float*)d_in[1];
    const float* v = (const float*)d_in[2];
    float* out = (float*)d_out;

    // Workspace (~26.7 MB), all fully rewritten each launch:
    _Float16* qhi = (_Float16*)d_ws;
    _Float16* qlo = qhi + QK;
    _Float16* khi = qlo + QK;
    float* smax_p = (float*)(khi + QK);       // 2*BHNN
    float* sden_p = smax_p + 2 * BHNN;        // 2*BHNN
    float* wpart  = sden_p + 2 * BHNN;        // 2*BHNN

    convert_kernel<<<QK / 4 / 256, 256, 0, stream>>>((const float4*)q, (const float4*)k,
                                                     qhi, qlo, khi);
    stats_kernel<<<1024, 256, 0, stream>>>(qhi, qlo, khi, smax_p, sden_p);
    wsum_kernel<<<1024, 256, 0, stream>>>(qhi, qlo, khi, smax_p, sden_p, wpart);
    out_kernel<<<(BH * NN * DD / 4) / 256, 256, 0, stream>>>(v, wpart, wpart + BHNN, out);
}

// Round 5
// 188.661 us; speedup vs baseline: 1.0202x; 1.0202x over previous
//
#include <hip/hip_runtime.h>
#include <math.h>

// q,k,v: [B=2, H=16, N=2048, Dh=64] fp32.  BH = 32 independent heads.
#define BH 32
#define NN 2048
#define DD 64
#define BHNN (BH * NN)        // 65536 rows total
#define QK ((size_t)BH * NN * DD)  // 4,194,304 elems per tensor

// 8 * log2(e): logits produced in base-2 domain so all softmax exps are a bare
// v_exp_f32 (exp2). Softmax is invariant to the base change.
#define QSCALE 11.5415603f

// Precision scheme (R11): fp16 q-hi/lo x fp16 k-single, 2 MFMAs per k-slice.
//
// R15 occupancy ledger (gfx950 UNIFIED VGPR+AGPR file):
//   Measured: acc[4] structure = ~80 arch + ~96 accum-side ~ 176 unified ->
//   ALWAYS 2 blocks/CU (R11 57.6us / R13 spilled trying / R14 no-spill but
//   still 24.5% occ). There is no 3-block operating point; the jump is
//   <=128 total -> 4 blocks/CU. acc[2] x 2 passes + global_load_lds staging
//   (no prefetch regs): 32 accum + 16 ah/al + 32 m/d + ~30 temps ~ 110 <= 128.
//   Grid 1024 = 4 x 256 CUs: one full resident round, zero tail.
//
// K layout (R14, kept): khi holds 16KB tiles [bh][tile][128 rows][64 cols],
// intra-row swizzle: 8-elem granule j stored at j ^ (row&7). global_load_lds
// stages LINEARLY; ds_read applies the same XOR (swizzle both sides).
typedef __attribute__((ext_vector_type(8)))  _Float16 halfx8;
typedef __attribute__((ext_vector_type(4)))  _Float16 halfx4;
typedef __attribute__((ext_vector_type(16))) float    floatx16;

__device__ inline float fexp2(float x) { return __builtin_amdgcn_exp2f(x); }
__device__ inline float flog2(float x) { return __builtin_amdgcn_logf(x); }

// C/D row for accumulator register r (0..15) given half = lane>>5 (verified R2).
__device__ inline int rowmap(int r, int half) {
    return (r & 3) + 8 * (r >> 2) + 4 * half;
}

// ---------------------------------------------------------------------------
// Pre-convert: q -> fp16 hi/lo (QSCALE folded), k -> fp16 single, swizzled.
// ---------------------------------------------------------------------------
__global__ __launch_bounds__(256) void convert_kernel(const float4* __restrict__ q,
                                                      const float4* __restrict__ k,
                                                      _Float16* __restrict__ qhi,
                                                      _Float16* __restrict__ qlo,
                                                      _Float16* __restrict__ khi) {
    size_t gid = (size_t)blockIdx.x * 256 + threadIdx.x;  // float4 index, QK/4 total
    float4 qa = q[gid];
    float4 ka = k[gid];
    float qf[4] = {qa.x, qa.y, qa.z, qa.w};
    float kf[4] = {ka.x, ka.y, ka.z, ka.w};
    halfx4 h, l, kh;
#pragma unroll
    for (int i = 0; i < 4; ++i) {
        float f = qf[i] * QSCALE;
        _Float16 hh = (_Float16)f;           // RN
        h[i] = hh;
        l[i] = (_Float16)(f - (float)hh);    // residual, RN
        kh[i] = (_Float16)kf[i];
    }
    *(halfx4*)&qhi[gid * 4] = h;
    *(halfx4*)&qlo[gid * 4] = l;
    // swizzled K: row = (gid>>4)&127; granule j = (gid>>1)&7; sub = (gid&1)*4
    size_t rowbase = (gid * 4) & ~(size_t)63;
    int j = (int)((gid >> 1) & 7) ^ (int)((gid >> 4) & 7);
    *(halfx4*)&khi[rowbase + (size_t)(j << 3) + ((gid & 1) << 2)] = kh;
}

// ---------------------------------------------------------------------------
// Async stage: one 16KB K-tile image -> LDS, linear copy, no VGPR round-trip.
// LDS dest = wave-uniform base + lane*16 (HW rule); global src per-lane.
// Tracked by vmcnt; __syncthreads() drains it.
// ---------------------------------------------------------------------------
__device__ inline void stage_tile_async(const _Float16* __restrict__ gtile,
                                        _Float16* lds, int wave, int lane) {
#pragma unroll
    for (int i = 0; i < 4; ++i) {
        const char* gp = (const char*)gtile + wave * 4096 + i * 1024 + lane * 16;
        char* lp = (char*)lds + wave * 4096 + i * 1024;   // wave-uniform
        __builtin_amdgcn_global_load_lds(
            (const __attribute__((address_space(1))) unsigned int*)gp,
            (__attribute__((address_space(3))) unsigned int*)lp, 16, 0, 0);
    }
}

// ---- A-operand fragments: lane holds A[m=lane&31][k=(lane>>5)*8+j] ----------
__device__ inline void load_a(const _Float16* __restrict__ qhi_row,
                              const _Float16* __restrict__ qlo_row,
                              int half, halfx8 ah[4], halfx8 al[4]) {
#pragma unroll
    for (int ks = 0; ks < 4; ++ks) {
        ah[ks] = *(const halfx8*)&qhi_row[ks * 16 + half * 8];
        al[ks] = *(const halfx8*)&qlo_row[ks * 16 + half * 8];
    }
}

// ---------------------------------------------------------------------------
// Phase 1: per-row softmax stats (base-2), PARTIAL over an m-half.
// 1D grid 1024: idx = (bh + 32*ms) + 64*nblk -> blocks sharing a K-half are
// congruent mod 8 => same XCD (L2 locality). Lazy per-lane online stats.
// acc[2] x 2 passes (unroll 1: passes' accs must not coexist) under
// __launch_bounds__(256,4). Double-buffered direct-to-LDS staging.
// ---------------------------------------------------------------------------
__global__ __launch_bounds__(256, 4) void stats_kernel(const _Float16* __restrict__ qhi,
                                                       const _Float16* __restrict__ qlo,
                                                       const _Float16* __restrict__ khi,
                                                       float* __restrict__ smax_p,
                                                       float* __restrict__ sden_p) {
    __shared__ _Float16 K2[2 * 128 * 64];  // 32 KB, two tile buffers
    const int g    = blockIdx.x & 63;      // bh + 32*ms
    const int bh   = g & 31;
    const int ms   = g >> 5;               // m-split: tiles [ms*8, ms*8+8)
    const int n0   = (blockIdx.x >> 6) * 128;
    const int tid  = threadIdx.x;
    const int wave = tid >> 6, lane = tid & 63;
    const int half = lane >> 5, l31 = lane & 31;
    const int xr   = l31 & 7;              // row&7 for swizzled reads (t*32 == 0 mod 8)
    const size_t base = (size_t)bh * NN * DD;

    const _Float16* khi_b = khi + base;
    stage_tile_async(khi_b + (size_t)(ms * 8) * 8192, K2, wave, lane);

    // A fragments: fixed rows for the whole kernel.
    halfx8 ah[4], al[4];
    {
        size_t ro = base + (size_t)(n0 + wave * 32 + l31) * DD;
        load_a(qhi + ro, qlo + ro, half, ah, al);
    }

    float m_run[16], d_run[16];
#pragma unroll
    for (int r = 0; r < 16; ++r) { m_run[r] = -INFINITY; d_run[r] = 0.f; }

    __syncthreads();                       // tile 0 landed (vmcnt drain) + barrier

#pragma unroll 1
    for (int mti = 0; mti < 8; ++mti) {
        const _Float16* Kc = K2 + (mti & 1) * 8192;
        if (mti < 7)                       // issue next tile BEFORE compute
            stage_tile_async(khi_b + (size_t)(ms * 8 + mti + 1) * 8192,
                             K2 + ((mti + 1) & 1) * 8192, wave, lane);

#pragma unroll 1
        for (int p = 0; p < 2; ++p) {      // two half-width passes: t = 2p+tt
            floatx16 acc[2];
#pragma unroll
            for (int t = 0; t < 2; ++t)
#pragma unroll
                for (int e = 0; e < 16; ++e) acc[t][e] = 0.f;

#pragma unroll
            for (int tt = 0; tt < 2; ++tt) {
                const int mr = (p * 2 + tt) * 32 + l31;
                const _Float16* rowp = Kc + (size_t)mr * 64;
#pragma unroll
                for (int ks = 0; ks < 4; ++ks) {
                    const int j = (ks * 2 + half) ^ xr;
                    halfx8 bhf = *(const halfx8*)&rowp[j << 3];
                    acc[tt] = __builtin_amdgcn_mfma_f32_32x32x16_f16(ah[ks], bhf, acc[tt], 0, 0, 0);
                    acc[tt] = __builtin_amdgcn_mfma_f32_32x32x16_f16(al[ks], bhf, acc[tt], 0, 0, 0);
                }
            }

            // Lazy per-lane online stats, base-2 domain.
#pragma unroll
            for (int r = 0; r < 16; ++r) {
                float tmax = fmaxf(acc[0][r], acc[1][r]);
                float m_new = fmaxf(m_run[r], tmax);
                float s = fexp2(acc[0][r] - m_new) + fexp2(acc[1][r] - m_new);
                d_run[r] = d_run[r] * fexp2(m_run[r] - m_new) + s;
                m_run[r] = m_new;
            }
        }

        if (mti < 7) __syncthreads();      // t+1 loads landed + all waves done with Kc
    }

    // Cross-lane combine within each 32-lane half (rows differ across halves).
    float* smp = smax_p + ((size_t)ms * BH + bh) * NN;
    float* sdp = sden_p + ((size_t)ms * BH + bh) * NN;
#pragma unroll
    for (int r = 0; r < 16; ++r) {
        float M = m_run[r];
#pragma unroll
        for (int off = 1; off < 32; off <<= 1)
            M = fmaxf(M, __shfl_xor(M, off));
        float dd = d_run[r] * fexp2(m_run[r] - M);
#pragma unroll
        for (int off = 1; off < 32; off <<= 1)
            dd += __shfl_xor(dd, off);
        if (l31 == 0) {
            int row = n0 + wave * 32 + rowmap(r, half);
            smp[row] = M;
            sdp[row] = dd;
        }
    }
}

// ---------------------------------------------------------------------------
// Phase 2: partial w[m] over an n-half. 1D grid 1024 with mod-8 XCD swizzle.
// Block owns 128 cols; K tile staged ONCE via global_load_lds. m-split
// combine folded into staging, storing Madj = M + log2(den): the r-loop is
// then exp2(acc - Madj) -- no inv multiply, no Is array (R15 VALU trim).
// acc[2] x 2 passes under __launch_bounds__(256,4).
// ---------------------------------------------------------------------------
__global__ __launch_bounds__(256, 4) void wsum_kernel(const _Float16* __restrict__ qhi,
                                                      const _Float16* __restrict__ qlo,
                                                      const _Float16* __restrict__ khi,
                                                      const float* __restrict__ smax_p,
                                                      const float* __restrict__ sden_p,
                                                      float* __restrict__ wpart) {
    __shared__ _Float16 Khi[128 * 64];     // 16 KB, single tile
    __shared__ float wred[4 * 128];
    __shared__ float Ms[1024];             // Madj = M + log2(den)
    const int g    = blockIdx.x & 63;      // bh + 32*nz
    const int bh   = g & 31;
    const int nz   = g >> 5;               // n-split: rows [nz*1024, +1024)
    const int m0   = (blockIdx.x >> 6) * 128;
    const int tid  = threadIdx.x;
    const int wave = tid >> 6, lane = tid & 63;
    const int half = lane >> 5, l31 = lane & 31;
    const int xr   = l31 & 7;
    const size_t base = (size_t)bh * NN * DD;

    stage_tile_async(khi + base + (size_t)m0 * 64, Khi, wave, lane);

    {   // combine row stats inline (4 rows/thread) while the tile streams in
        size_t roff = (size_t)bh * NN + nz * 1024 + tid * 4;
        float4 m0v = *(const float4*)&smax_p[roff];
        float4 m1v = *(const float4*)&smax_p[(size_t)BHNN + roff];
        float4 d0v = *(const float4*)&sden_p[roff];
        float4 d1v = *(const float4*)&sden_p[(size_t)BHNN + roff];
        float mm0[4] = {m0v.x, m0v.y, m0v.z, m0v.w};
        float mm1[4] = {m1v.x, m1v.y, m1v.z, m1v.w};
        float dd0[4] = {d0v.x, d0v.y, d0v.z, d0v.w};
        float dd1[4] = {d1v.x, d1v.y, d1v.z, d1v.w};
#pragma unroll
        for (int j = 0; j < 4; ++j) {
            float M = fmaxf(mm0[j], mm1[j]);
            float den = dd0[j] * fexp2(mm0[j] - M) + dd1[j] * fexp2(mm1[j] - M);
            Ms[tid * 4 + j] = M + flog2(den);
        }
    }
    __syncthreads();                       // K tile landed + Ms visible

    float wacc0 = 0.f, wacc1 = 0.f, wacc2 = 0.f, wacc3 = 0.f;

#pragma unroll 1
    for (int it = 0; it < 8; ++it) {
        const int ls = wave + it * 4;      // local strip 0..31
        halfx8 ah[4], al[4];
        {
            size_t ro = base + (size_t)((nz * 32 + ls) * 32 + l31) * DD;
            load_a(qhi + ro, qlo + ro, half, ah, al);
        }

#pragma unroll 1
        for (int p = 0; p < 2; ++p) {
            floatx16 acc[2];
#pragma unroll
            for (int t = 0; t < 2; ++t)
#pragma unroll
                for (int e = 0; e < 16; ++e) acc[t][e] = 0.f;

#pragma unroll
            for (int tt = 0; tt < 2; ++tt) {
                const int mr = (p * 2 + tt) * 32 + l31;
                const _Float16* rowp = Khi + (size_t)mr * 64;
#pragma unroll
                for (int ks = 0; ks < 4; ++ks) {
                    const int j = (ks * 2 + half) ^ xr;
                    halfx8 bhf = *(const halfx8*)&rowp[j << 3];
                    acc[tt] = __builtin_amdgcn_mfma_f32_32x32x16_f16(ah[ks], bhf, acc[tt], 0, 0, 0);
                    acc[tt] = __builtin_amdgcn_mfma_f32_32x32x16_f16(al[ks], bhf, acc[tt], 0, 0, 0);
                }
            }

            float w0 = 0.f, w1 = 0.f;
#pragma unroll
            for (int r = 0; r < 16; ++r) {
                const int lrow = ls * 32 + rowmap(r, half);   // broadcast LDS read
                float Madj = Ms[lrow];
                w0 += fexp2(acc[0][r] - Madj);
                w1 += fexp2(acc[1][r] - Madj);
            }
            if (p == 0) { wacc0 += w0; wacc1 += w1; }
            else        { wacc2 += w0; wacc3 += w1; }
        }
    }

    // halves hold same cols, different rows: sum across halves, then waves.
    float wacc[4] = {wacc0, wacc1, wacc2, wacc3};
#pragma unroll
    for (int t = 0; t < 4; ++t) wacc[t] += __shfl_xor(wacc[t], 32);
    if (half == 0) {
#pragma unroll
        for (int t = 0; t < 4; ++t) wred[wave * 128 + t * 32 + l31] = wacc[t];
    }
    __syncthreads();
    if (tid < 128) {
        float s = wred[tid] + wred[128 + tid] + wred[256 + tid] + wred[384 + tid];
        wpart[((size_t)nz * BH + bh) * NN + m0 + tid] = s;
    }
}

// ---------------------------------------------------------------------------
// Phase 3: out[b,h,m,d] = (w0[m]+w1[m]) * v[b,h,m,d]
// ---------------------------------------------------------------------------
__global__ __launch_bounds__(256) void out_kernel(const float* __restrict__ v,
                                                  const float* __restrict__ w0,
                                                  const float* __restrict__ w1,
                                                  float* __restrict__ out) {
    size_t gid = (size_t)blockIdx.x * 256 + threadIdx.x;  // float4 index
    const float4* v4 = (const float4*)v;
    float4* o4 = (float4*)out;
    float4 vv = v4[gid];
    float ww = w0[gid >> 4] + w1[gid >> 4];
    o4[gid] = make_float4(vv.x * ww, vv.y * ww, vv.z * ww, vv.w * ww);
}

extern "C" void kernel_launch(void* const* d_in, const int* in_sizes, int n_in,
                              void* d_out, int out_size, void* d_ws, size_t ws_size,
                              hipStream_t stream) {
    const float* q = (const float*)d_in[0];
    const float* k = (const float*)d_in[1];
    const float* v = (const float*)d_in[2];
    float* out = (float*)d_out;

    // Workspace (~26.7 MB), all fully rewritten each launch:
    _Float16* qhi = (_Float16*)d_ws;
    _Float16* qlo = qhi + QK;
    _Float16* khi = qlo + QK;
    float* smax_p = (float*)(khi + QK);       // 2*BHNN
    float* sden_p = smax_p + 2 * BHNN;        // 2*BHNN
    float* wpart  = sden_p + 2 * BHNN;        // 2*BHNN

    convert_kernel<<<QK / 4 / 256, 256, 0, stream>>>((const float4*)q, (const float4*)k,
                                                     qhi, qlo, khi);
    stats_kernel<<<1024, 256, 0, stream>>>(qhi, qlo, khi, smax_p, sden_p);
    wsum_kernel<<<1024, 256, 0, stream>>>(qhi, qlo, khi, smax_p, sden_p, wpart);
    out_kernel<<<(BH * NN * DD / 4) / 256, 256, 0, stream>>>(v, wpart, wpart + BHNN, out);
}

// Round 6
// 160.699 us; speedup vs baseline: 1.1977x; 1.1740x over previous
//
#include <hip/hip_runtime.h>
#include <math.h>

// q,k,v: [B=2, H=16, N=2048, Dh=64] fp32.  BH = 32 independent heads.
#define BH 32
#define NN 2048
#define DD 64
#define BHNN (BH * NN)        // 65536 rows total
#define QK ((size_t)BH * NN * DD)  // 4,194,304 elems per tensor

// 8 * log2(e): logits produced in base-2 domain so all softmax exps are a bare
// v_exp_f32 (exp2). Softmax is invariant to the base change.
#define QSCALE 11.5415603f

// R16 precision scheme: SINGLE fp16 q x fp16 k MFMA per k-slice.
//   Error ledger (base-2 logit domain, logit sigma ~ 92):
//     k-single rounding: sigma ~ 0.026 (R11+, absmax 0.25)
//     + q-single rounding: sigma ~ 0.023 -> combined ~ 0.035.
//   absmax stayed EXACTLY 0.25 from bf16-hi/lo (sigma 0.004) through fp16
//   k-single (0.026): the 0.25 is the fp32-reference quirk, not our logits.
//
// R16 register ledger (gfx950 UNIFIED VGPR+AGPR file; spill history:
//   R12 23MB / R13 5MB / R15 15MB -- every variant with ah+al (32 regs of A)
//   exceeded cap 128). Dropping q-lo removes al (16 regs) AND halves MFMAs:
//   acc[2]=32 + ah=16 + m/d_run=32 + temps ~25 => ~105 <= 128.
//   __launch_bounds__(256,4): 4 blocks/CU, grid 1024 = 4 x 256 CUs exactly.
//
// K layout (R14, kept): khi holds 16KB tiles [bh][tile][128 rows][64 cols],
// intra-row swizzle: 8-elem granule j stored at j ^ (row&7). global_load_lds
// stages LINEARLY; ds_read applies the same XOR (swizzle both sides).
// Sync structure (R14, kept): stage(t+1) -> compute(t) -> __syncthreads.
// Compute (~1000 cyc) covers the load latency; counted-vmcnt buys nothing.
typedef __attribute__((ext_vector_type(8)))  _Float16 halfx8;
typedef __attribute__((ext_vector_type(4)))  _Float16 halfx4;
typedef __attribute__((ext_vector_type(16))) float    floatx16;

__device__ inline float fexp2(float x) { return __builtin_amdgcn_exp2f(x); }
__device__ inline float flog2(float x) { return __builtin_amdgcn_logf(x); }

// C/D row for accumulator register r (0..15) given half = lane>>5 (verified R2).
__device__ inline int rowmap(int r, int half) {
    return (r & 3) + 8 * (r >> 2) + 4 * half;
}

// ---------------------------------------------------------------------------
// Pre-convert: q -> fp16 (QSCALE folded), k -> fp16, k swizzled.
// ---------------------------------------------------------------------------
__global__ __launch_bounds__(256) void convert_kernel(const float4* __restrict__ q,
                                                      const float4* __restrict__ k,
                                                      _Float16* __restrict__ qhi,
                                                      _Float16* __restrict__ khi) {
    size_t gid = (size_t)blockIdx.x * 256 + threadIdx.x;  // float4 index, QK/4 total
    float4 qa = q[gid];
    float4 ka = k[gid];
    float qf[4] = {qa.x, qa.y, qa.z, qa.w};
    float kf[4] = {ka.x, ka.y, ka.z, ka.w};
    halfx4 h, kh;
#pragma unroll
    for (int i = 0; i < 4; ++i) {
        h[i]  = (_Float16)(qf[i] * QSCALE);  // RN
        kh[i] = (_Float16)kf[i];
    }
    *(halfx4*)&qhi[gid * 4] = h;
    // swizzled K: row = (gid>>4)&127; granule j = (gid>>1)&7; sub = (gid&1)*4
    size_t rowbase = (gid * 4) & ~(size_t)63;
    int j = (int)((gid >> 1) & 7) ^ (int)((gid >> 4) & 7);
    *(halfx4*)&khi[rowbase + (size_t)(j << 3) + ((gid & 1) << 2)] = kh;
}

// ---------------------------------------------------------------------------
// Async stage: one 16KB K-tile image -> LDS, linear copy, no VGPR round-trip.
// LDS dest = wave-uniform base + lane*16 (HW rule); global src per-lane.
// Tracked by vmcnt; __syncthreads() drains it.
// ---------------------------------------------------------------------------
__device__ inline void stage_tile_async(const _Float16* __restrict__ gtile,
                                        _Float16* lds, int wave, int lane) {
#pragma unroll
    for (int i = 0; i < 4; ++i) {
        const char* gp = (const char*)gtile + wave * 4096 + i * 1024 + lane * 16;
        char* lp = (char*)lds + wave * 4096 + i * 1024;   // wave-uniform
        __builtin_amdgcn_global_load_lds(
            (const __attribute__((address_space(1))) unsigned int*)gp,
            (__attribute__((address_space(3))) unsigned int*)lp, 16, 0, 0);
    }
}

// ---- A-operand fragments: lane holds A[m=lane&31][k=(lane>>5)*8+j] ----------
__device__ inline void load_a(const _Float16* __restrict__ qhi_row,
                              int half, halfx8 ah[4]) {
#pragma unroll
    for (int ks = 0; ks < 4; ++ks)
        ah[ks] = *(const halfx8*)&qhi_row[ks * 16 + half * 8];
}

// ---------------------------------------------------------------------------
// Phase 1: per-row softmax stats (base-2), PARTIAL over an m-half.
// 1D grid 1024: idx = (bh + 32*ms) + 64*nblk -> blocks sharing a K-half are
// congruent mod 8 => same XCD (L2 locality). Lazy per-lane online stats.
// acc[2] x 2 passes (unroll 1: passes' accs must not coexist) under
// __launch_bounds__(256,4). Double-buffered direct-to-LDS staging.
// ---------------------------------------------------------------------------
__global__ __launch_bounds__(256, 4) void stats_kernel(const _Float16* __restrict__ qhi,
                                                       const _Float16* __restrict__ khi,
                                                       float* __restrict__ smax_p,
                                                       float* __restrict__ sden_p) {
    __shared__ _Float16 K2[2 * 128 * 64];  // 32 KB, two tile buffers
    const int g    = blockIdx.x & 63;      // bh + 32*ms
    const int bh   = g & 31;
    const int ms   = g >> 5;               // m-split: tiles [ms*8, ms*8+8)
    const int n0   = (blockIdx.x >> 6) * 128;
    const int tid  = threadIdx.x;
    const int wave = tid >> 6, lane = tid & 63;
    const int half = lane >> 5, l31 = lane & 31;
    const int xr   = l31 & 7;              // row&7 for swizzled reads (t*32 == 0 mod 8)
    const size_t base = (size_t)bh * NN * DD;

    const _Float16* khi_b = khi + base;
    stage_tile_async(khi_b + (size_t)(ms * 8) * 8192, K2, wave, lane);

    // A fragments: fixed rows for the whole kernel.
    halfx8 ah[4];
    {
        size_t ro = base + (size_t)(n0 + wave * 32 + l31) * DD;
        load_a(qhi + ro, half, ah);
    }

    float m_run[16], d_run[16];
#pragma unroll
    for (int r = 0; r < 16; ++r) { m_run[r] = -INFINITY; d_run[r] = 0.f; }

    __syncthreads();                       // tile 0 landed (vmcnt drain) + barrier

#pragma unroll 1
    for (int mti = 0; mti < 8; ++mti) {
        const _Float16* Kc = K2 + (mti & 1) * 8192;
        if (mti < 7)                       // issue next tile BEFORE compute
            stage_tile_async(khi_b + (size_t)(ms * 8 + mti + 1) * 8192,
                             K2 + ((mti + 1) & 1) * 8192, wave, lane);

#pragma unroll 1
        for (int p = 0; p < 2; ++p) {      // two half-width passes: t = 2p+tt
            floatx16 acc[2];
#pragma unroll
            for (int t = 0; t < 2; ++t)
#pragma unroll
                for (int e = 0; e < 16; ++e) acc[t][e] = 0.f;

#pragma unroll
            for (int tt = 0; tt < 2; ++tt) {
                const int mr = (p * 2 + tt) * 32 + l31;
                const _Float16* rowp = Kc + (size_t)mr * 64;
#pragma unroll
                for (int ks = 0; ks < 4; ++ks) {
                    const int j = (ks * 2 + half) ^ xr;
                    halfx8 bhf = *(const halfx8*)&rowp[j << 3];
                    acc[tt] = __builtin_amdgcn_mfma_f32_32x32x16_f16(ah[ks], bhf, acc[tt], 0, 0, 0);
                }
            }

            // Lazy per-lane online stats, base-2 domain.
#pragma unroll
            for (int r = 0; r < 16; ++r) {
                float tmax = fmaxf(acc[0][r], acc[1][r]);
                float m_new = fmaxf(m_run[r], tmax);
                float s = fexp2(acc[0][r] - m_new) + fexp2(acc[1][r] - m_new);
                d_run[r] = d_run[r] * fexp2(m_run[r] - m_new) + s;
                m_run[r] = m_new;
            }
        }

        if (mti < 7) __syncthreads();      // t+1 loads landed + all waves done with Kc
    }

    // Cross-lane combine within each 32-lane half (rows differ across halves).
    float* smp = smax_p + ((size_t)ms * BH + bh) * NN;
    float* sdp = sden_p + ((size_t)ms * BH + bh) * NN;
#pragma unroll
    for (int r = 0; r < 16; ++r) {
        float M = m_run[r];
#pragma unroll
        for (int off = 1; off < 32; off <<= 1)
            M = fmaxf(M, __shfl_xor(M, off));
        float dd = d_run[r] * fexp2(m_run[r] - M);
#pragma unroll
        for (int off = 1; off < 32; off <<= 1)
            dd += __shfl_xor(dd, off);
        if (l31 == 0) {
            int row = n0 + wave * 32 + rowmap(r, half);
            smp[row] = M;
            sdp[row] = dd;
        }
    }
}

// ---------------------------------------------------------------------------
// Phase 2: partial w[m] over an n-half. 1D grid 1024 with mod-8 XCD swizzle.
// Block owns 128 cols; K tile staged ONCE via global_load_lds. m-split
// combine folded into staging, storing Madj = M + log2(den): the r-loop is
// then exp2(acc - Madj) -- no inv multiply, no Is array.
// acc[2] x 2 passes under __launch_bounds__(256,4).
// ---------------------------------------------------------------------------
__global__ __launch_bounds__(256, 4) void wsum_kernel(const _Float16* __restrict__ qhi,
                                                      const _Float16* __restrict__ khi,
                                                      const float* __restrict__ smax_p,
                                                      const float* __restrict__ sden_p,
                                                      float* __restrict__ wpart) {
    __shared__ _Float16 Khi[128 * 64];     // 16 KB, single tile
    __shared__ float wred[4 * 128];
    __shared__ float Ms[1024];             // Madj = M + log2(den)
    const int g    = blockIdx.x & 63;      // bh + 32*nz
    const int bh   = g & 31;
    const int nz   = g >> 5;               // n-split: rows [nz*1024, +1024)
    const int m0   = (blockIdx.x >> 6) * 128;
    const int tid  = threadIdx.x;
    const int wave = tid >> 6, lane = tid & 63;
    const int half = lane >> 5, l31 = lane & 31;
    const int xr   = l31 & 7;
    const size_t base = (size_t)bh * NN * DD;

    stage_tile_async(khi + base + (size_t)m0 * 64, Khi, wave, lane);

    {   // combine row stats inline (4 rows/thread) while the tile streams in
        size_t roff = (size_t)bh * NN + nz * 1024 + tid * 4;
        float4 m0v = *(const float4*)&smax_p[roff];
        float4 m1v = *(const float4*)&smax_p[(size_t)BHNN + roff];
        float4 d0v = *(const float4*)&sden_p[roff];
        float4 d1v = *(const float4*)&sden_p[(size_t)BHNN + roff];
        float mm0[4] = {m0v.x, m0v.y, m0v.z, m0v.w};
        float mm1[4] = {m1v.x, m1v.y, m1v.z, m1v.w};
        float dd0[4] = {d0v.x, d0v.y, d0v.z, d0v.w};
        float dd1[4] = {d1v.x, d1v.y, d1v.z, d1v.w};
#pragma unroll
        for (int j = 0; j < 4; ++j) {
            float M = fmaxf(mm0[j], mm1[j]);
            float den = dd0[j] * fexp2(mm0[j] - M) + dd1[j] * fexp2(mm1[j] - M);
            Ms[tid * 4 + j] = M + flog2(den);
        }
    }
    __syncthreads();                       // K tile landed + Ms visible

    float wacc0 = 0.f, wacc1 = 0.f, wacc2 = 0.f, wacc3 = 0.f;

#pragma unroll 1
    for (int it = 0; it < 8; ++it) {
        const int ls = wave + it * 4;      // local strip 0..31
        halfx8 ah[4];
        {
            size_t ro = base + (size_t)((nz * 32 + ls) * 32 + l31) * DD;
            load_a(qhi + ro, half, ah);
        }

#pragma unroll 1
        for (int p = 0; p < 2; ++p) {
            floatx16 acc[2];
#pragma unroll
            for (int t = 0; t < 2; ++t)
#pragma unroll
                for (int e = 0; e < 16; ++e) acc[t][e] = 0.f;

#pragma unroll
            for (int tt = 0; tt < 2; ++tt) {
                const int mr = (p * 2 + tt) * 32 + l31;
                const _Float16* rowp = Khi + (size_t)mr * 64;
#pragma unroll
                for (int ks = 0; ks < 4; ++ks) {
                    const int j = (ks * 2 + half) ^ xr;
                    halfx8 bhf = *(const halfx8*)&rowp[j << 3];
                    acc[tt] = __builtin_amdgcn_mfma_f32_32x32x16_f16(ah[ks], bhf, acc[tt], 0, 0, 0);
                }
            }

            float w0 = 0.f, w1 = 0.f;
#pragma unroll
            for (int r = 0; r < 16; ++r) {
                const int lrow = ls * 32 + rowmap(r, half);   // broadcast LDS read
                float Madj = Ms[lrow];
                w0 += fexp2(acc[0][r] - Madj);
                w1 += fexp2(acc[1][r] - Madj);
            }
            if (p == 0) { wacc0 += w0; wacc1 += w1; }
            else        { wacc2 += w0; wacc3 += w1; }
        }
    }

    // halves hold same cols, different rows: sum across halves, then waves.
    float wacc[4] = {wacc0, wacc1, wacc2, wacc3};
#pragma unroll
    for (int t = 0; t < 4; ++t) wacc[t] += __shfl_xor(wacc[t], 32);
    if (half == 0) {
#pragma unroll
        for (int t = 0; t < 4; ++t) wred[wave * 128 + t * 32 + l31] = wacc[t];
    }
    __syncthreads();
    if (tid < 128) {
        float s = wred[tid] + wred[128 + tid] + wred[256 + tid] + wred[384 + tid];
        wpart[((size_t)nz * BH + bh) * NN + m0 + tid] = s;
    }
}

// ---------------------------------------------------------------------------
// Phase 3: out[b,h,m,d] = (w0[m]+w1[m]) * v[b,h,m,d]
// ---------------------------------------------------------------------------
__global__ __launch_bounds__(256) void out_kernel(const float* __restrict__ v,
                                                  const float* __restrict__ w0,
                                                  const float* __restrict__ w1,
                                                  float* __restrict__ out) {
    size_t gid = (size_t)blockIdx.x * 256 + threadIdx.x;  // float4 index
    const float4* v4 = (const float4*)v;
    float4* o4 = (float4*)out;
    float4 vv = v4[gid];
    float ww = w0[gid >> 4] + w1[gid >> 4];
    o4[gid] = make_float4(vv.x * ww, vv.y * ww, vv.z * ww, vv.w * ww);
}

extern "C" void kernel_launch(void* const* d_in, const int* in_sizes, int n_in,
                              void* d_out, int out_size, void* d_ws, size_t ws_size,
                              hipStream_t stream) {
    const float* q = (const float*)d_in[0];
    const float* k = (const float*)d_in[1];
    const float* v = (const float*)d_in[2];
    float* out = (float*)d_out;

    // Workspace (~18.8 MB), all fully rewritten each launch:
    _Float16* qhi = (_Float16*)d_ws;
    _Float16* khi = qhi + QK;
    float* smax_p = (float*)(khi + QK);       // 2*BHNN
    float* sden_p = smax_p + 2 * BHNN;        // 2*BHNN
    float* wpart  = sden_p + 2 * BHNN;        // 2*BHNN

    convert_kernel<<<QK / 4 / 256, 256, 0, stream>>>((const float4*)q, (const float4*)k,
                                                     qhi, khi);
    stats_kernel<<<1024, 256, 0, stream>>>(qhi, khi, smax_p, sden_p);
    wsum_kernel<<<1024, 256, 0, stream>>>(qhi, khi, smax_p, sden_p, wpart);
    out_kernel<<<(BH * NN * DD / 4) / 256, 256, 0, stream>>>(v, wpart, wpart + BHNN, out);
}

// Round 7
// 159.518 us; speedup vs baseline: 1.2066x; 1.0074x over previous
//
#include <hip/hip_runtime.h>
#include <math.h>

// q,k,v: [B=2, H=16, N=2048, Dh=64] fp32.  BH = 32 independent heads.
#define BH 32
#define NN 2048
#define DD 64
#define BHNN (BH * NN)        // 65536 rows total
#define QK ((size_t)BH * NN * DD)  // 4,194,304 elems per tensor

// 8 * log2(e): logits produced in base-2 domain so all softmax exps are a bare
// v_exp_f32 (exp2). Softmax is invariant to the base change.
#define QSCALE 11.5415603f

// R16 precision scheme (kept): SINGLE fp16 q x fp16 k MFMA per k-slice.
// absmax stayed exactly 0.25 from sigma 0.004 through 0.035 schemes: the
// 0.25 is the fp32-reference quirk, not our logit precision.
//
// R17 structural change: ~50us of the R6 wall time (160.7 total vs ~110 of
// kernel time) is inter-dispatch gap (~12us/launch, consistent R0-R6).
// => fuse out_kernel into wsum: each wsum block owns ALL 2048 rows for its
// 128 cols (grid 512 x 512thr, __launch_bounds__(512,4) -> same 4 waves/SIMD,
// grid = 2 x 256 CUs exactly). n-split gone -> block-complete col sums ->
// multiply v rows [m0,m0+128) and write out directly. No atomics, no wpart,
// no out kernel. XCD locality: blockIdx mod 8 = bh mod 8 keeps each head's
// 16 blocks on one XCD for the shared Q-row L2 reads.
//
// Register ledger (unified VGPR+AGPR, cap 128 at 4 waves/SIMD -- spill
// history R12/R13/R15): acc[2]=32 + ah=16 + m/d or wacc + temps ~ 110 <= 128.
//
// K layout (R14, kept): khi = 16KB tiles [bh][tile][128 rows][64 cols],
// intra-row swizzle: granule j at j ^ (row&7). global_load_lds stages
// LINEARLY; ds_read applies the same XOR (swizzle both sides or neither).
typedef __attribute__((ext_vector_type(8)))  _Float16 halfx8;
typedef __attribute__((ext_vector_type(4)))  _Float16 halfx4;
typedef __attribute__((ext_vector_type(16))) float    floatx16;

__device__ inline float fexp2(float x) { return __builtin_amdgcn_exp2f(x); }
__device__ inline float flog2(float x) { return __builtin_amdgcn_logf(x); }

// C/D row for accumulator register r (0..15) given half = lane>>5 (verified R2).
__device__ inline int rowmap(int r, int half) {
    return (r & 3) + 8 * (r >> 2) + 4 * half;
}

// ---------------------------------------------------------------------------
// Pre-convert: q -> fp16 (QSCALE folded), k -> fp16, k swizzled.
// ---------------------------------------------------------------------------
__global__ __launch_bounds__(256) void convert_kernel(const float4* __restrict__ q,
                                                      const float4* __restrict__ k,
                                                      _Float16* __restrict__ qhi,
                                                      _Float16* __restrict__ khi) {
    size_t gid = (size_t)blockIdx.x * 256 + threadIdx.x;  // float4 index, QK/4 total
    float4 qa = q[gid];
    float4 ka = k[gid];
    float qf[4] = {qa.x, qa.y, qa.z, qa.w};
    float kf[4] = {ka.x, ka.y, ka.z, ka.w};
    halfx4 h, kh;
#pragma unroll
    for (int i = 0; i < 4; ++i) {
        h[i]  = (_Float16)(qf[i] * QSCALE);  // RN
        kh[i] = (_Float16)kf[i];
    }
    *(halfx4*)&qhi[gid * 4] = h;
    // swizzled K: row = (gid>>4)&127; granule j = (gid>>1)&7; sub = (gid&1)*4
    size_t rowbase = (gid * 4) & ~(size_t)63;
    int j = (int)((gid >> 1) & 7) ^ (int)((gid >> 4) & 7);
    *(halfx4*)&khi[rowbase + (size_t)(j << 3) + ((gid & 1) << 2)] = kh;
}

// ---------------------------------------------------------------------------
// Async stage: one 16KB K-tile image -> LDS, linear copy, no VGPR round-trip.
// LDS dest = wave-uniform base + lane*16 (HW rule); global src per-lane.
// Tracked by vmcnt; __syncthreads() drains it.  4-wave and 8-wave variants.
// ---------------------------------------------------------------------------
__device__ inline void stage_tile_async4(const _Float16* __restrict__ gtile,
                                         _Float16* lds, int wave, int lane) {
#pragma unroll
    for (int i = 0; i < 4; ++i) {
        const char* gp = (const char*)gtile + wave * 4096 + i * 1024 + lane * 16;
        char* lp = (char*)lds + wave * 4096 + i * 1024;   // wave-uniform
        __builtin_amdgcn_global_load_lds(
            (const __attribute__((address_space(1))) unsigned int*)gp,
            (__attribute__((address_space(3))) unsigned int*)lp, 16, 0, 0);
    }
}
__device__ inline void stage_tile_async8(const _Float16* __restrict__ gtile,
                                         _Float16* lds, int wave, int lane) {
#pragma unroll
    for (int i = 0; i < 2; ++i) {
        const char* gp = (const char*)gtile + wave * 2048 + i * 1024 + lane * 16;
        char* lp = (char*)lds + wave * 2048 + i * 1024;   // wave-uniform
        __builtin_amdgcn_global_load_lds(
            (const __attribute__((address_space(1))) unsigned int*)gp,
            (__attribute__((address_space(3))) unsigned int*)lp, 16, 0, 0);
    }
}

// ---- A-operand fragments: lane holds A[m=lane&31][k=(lane>>5)*8+j] ----------
__device__ inline void load_a(const _Float16* __restrict__ qhi_row,
                              int half, halfx8 ah[4]) {
#pragma unroll
    for (int ks = 0; ks < 4; ++ks)
        ah[ks] = *(const halfx8*)&qhi_row[ks * 16 + half * 8];
}

// ---------------------------------------------------------------------------
// Phase 1: per-row softmax stats (base-2), PARTIAL over an m-half.
// 1D grid 1024: idx = (bh + 32*ms) + 64*nblk -> blocks sharing a K-half are
// congruent mod 8 => same XCD (L2 locality). Lazy per-lane online stats.
// acc[2] x 2 passes (unroll 1: passes' accs must not coexist) under
// __launch_bounds__(256,4). Double-buffered direct-to-LDS staging.
// ---------------------------------------------------------------------------
__global__ __launch_bounds__(256, 4) void stats_kernel(const _Float16* __restrict__ qhi,
                                                       const _Float16* __restrict__ khi,
                                                       float* __restrict__ smax_p,
                                                       float* __restrict__ sden_p) {
    __shared__ _Float16 K2[2 * 128 * 64];  // 32 KB, two tile buffers
    const int g    = blockIdx.x & 63;      // bh + 32*ms
    const int bh   = g & 31;
    const int ms   = g >> 5;               // m-split: tiles [ms*8, ms*8+8)
    const int n0   = (blockIdx.x >> 6) * 128;
    const int tid  = threadIdx.x;
    const int wave = tid >> 6, lane = tid & 63;
    const int half = lane >> 5, l31 = lane & 31;
    const int xr   = l31 & 7;              // row&7 for swizzled reads (t*32 == 0 mod 8)
    const size_t base = (size_t)bh * NN * DD;

    const _Float16* khi_b = khi + base;
    stage_tile_async4(khi_b + (size_t)(ms * 8) * 8192, K2, wave, lane);

    // A fragments: fixed rows for the whole kernel.
    halfx8 ah[4];
    {
        size_t ro = base + (size_t)(n0 + wave * 32 + l31) * DD;
        load_a(qhi + ro, half, ah);
    }

    float m_run[16], d_run[16];
#pragma unroll
    for (int r = 0; r < 16; ++r) { m_run[r] = -INFINITY; d_run[r] = 0.f; }

    __syncthreads();                       // tile 0 landed (vmcnt drain) + barrier

#pragma unroll 1
    for (int mti = 0; mti < 8; ++mti) {
        const _Float16* Kc = K2 + (mti & 1) * 8192;
        if (mti < 7)                       // issue next tile BEFORE compute
            stage_tile_async4(khi_b + (size_t)(ms * 8 + mti + 1) * 8192,
                              K2 + ((mti + 1) & 1) * 8192, wave, lane);

#pragma unroll 1
        for (int p = 0; p < 2; ++p) {      // two half-width passes: t = 2p+tt
            floatx16 acc[2];
#pragma unroll
            for (int t = 0; t < 2; ++t)
#pragma unroll
                for (int e = 0; e < 16; ++e) acc[t][e] = 0.f;

#pragma unroll
            for (int tt = 0; tt < 2; ++tt) {
                const int mr = (p * 2 + tt) * 32 + l31;
                const _Float16* rowp = Kc + (size_t)mr * 64;
#pragma unroll
                for (int ks = 0; ks < 4; ++ks) {
                    const int j = (ks * 2 + half) ^ xr;
                    halfx8 bhf = *(const halfx8*)&rowp[j << 3];
                    acc[tt] = __builtin_amdgcn_mfma_f32_32x32x16_f16(ah[ks], bhf, acc[tt], 0, 0, 0);
                }
            }

            // Lazy per-lane online stats, base-2 domain.
#pragma unroll
            for (int r = 0; r < 16; ++r) {
                float tmax = fmaxf(acc[0][r], acc[1][r]);
                float m_new = fmaxf(m_run[r], tmax);
                float s = fexp2(acc[0][r] - m_new) + fexp2(acc[1][r] - m_new);
                d_run[r] = d_run[r] * fexp2(m_run[r] - m_new) + s;
                m_run[r] = m_new;
            }
        }

        if (mti < 7) __syncthreads();      // t+1 loads landed + all waves done with Kc
    }

    // Cross-lane combine within each 32-lane half (rows differ across halves).
    float* smp = smax_p + ((size_t)ms * BH + bh) * NN;
    float* sdp = sden_p + ((size_t)ms * BH + bh) * NN;
#pragma unroll
    for (int r = 0; r < 16; ++r) {
        float M = m_run[r];
#pragma unroll
        for (int off = 1; off < 32; off <<= 1)
            M = fmaxf(M, __shfl_xor(M, off));
        float dd = d_run[r] * fexp2(m_run[r] - M);
#pragma unroll
        for (int off = 1; off < 32; off <<= 1)
            dd += __shfl_xor(dd, off);
        if (l31 == 0) {
            int row = n0 + wave * 32 + rowmap(r, half);
            smp[row] = M;
            sdp[row] = dd;
        }
    }
}

// ---------------------------------------------------------------------------
// Phase 2 (R17): w[m] over ALL rows + fused output.  Grid 512 = bh + 32*m0i,
// 512 threads (8 waves).  Block owns 128 cols; K tile staged once; the 8
// waves stride 64 row-strips of 32.  Per-row Madj = M + log2(den) staged in
// LDS from the stats partials.  Block-complete col sums -> multiply v rows
// [m0, m0+128) and write out directly (no wpart, no out_kernel).
// ---------------------------------------------------------------------------
__global__ __launch_bounds__(512, 4) void wsum_kernel(const _Float16* __restrict__ qhi,
                                                      const _Float16* __restrict__ khi,
                                                      const float* __restrict__ smax_p,
                                                      const float* __restrict__ sden_p,
                                                      const float* __restrict__ v,
                                                      float* __restrict__ out) {
    __shared__ _Float16 Khi[128 * 64];     // 16 KB, single tile
    __shared__ float Ms[2048];             // 8 KB: Madj for all rows of bh
    __shared__ float wred[8 * 128];        // 4 KB
    __shared__ float wfin[128];
    const int b    = blockIdx.x;
    const int bh   = b & 31;
    const int m0   = (b >> 5) * 128;       // col block
    const int tid  = threadIdx.x;
    const int wave = tid >> 6, lane = tid & 63;
    const int half = lane >> 5, l31 = lane & 31;
    const int xr   = l31 & 7;
    const size_t base = (size_t)bh * NN * DD;

    stage_tile_async8(khi + base + (size_t)m0 * 64, Khi, wave, lane);

    {   // combine row stats inline (4 rows/thread) while the tile streams in
        size_t roff = (size_t)bh * NN + tid * 4;
        float4 m0v = *(const float4*)&smax_p[roff];
        float4 m1v = *(const float4*)&smax_p[(size_t)BHNN + roff];
        float4 d0v = *(const float4*)&sden_p[roff];
        float4 d1v = *(const float4*)&sden_p[(size_t)BHNN + roff];
        float mm0[4] = {m0v.x, m0v.y, m0v.z, m0v.w};
        float mm1[4] = {m1v.x, m1v.y, m1v.z, m1v.w};
        float dd0[4] = {d0v.x, d0v.y, d0v.z, d0v.w};
        float dd1[4] = {d1v.x, d1v.y, d1v.z, d1v.w};
#pragma unroll
        for (int j = 0; j < 4; ++j) {
            float M = fmaxf(mm0[j], mm1[j]);
            float den = dd0[j] * fexp2(mm0[j] - M) + dd1[j] * fexp2(mm1[j] - M);
            Ms[tid * 4 + j] = M + flog2(den);
        }
    }
    __syncthreads();                       // K tile landed + Ms visible

    float wacc0 = 0.f, wacc1 = 0.f, wacc2 = 0.f, wacc3 = 0.f;

#pragma unroll 1
    for (int it = 0; it < 8; ++it) {
        const int ls = wave + it * 8;      // local strip 0..63 (32 rows each)
        halfx8 ah[4];
        {
            size_t ro = base + (size_t)(ls * 32 + l31) * DD;
            load_a(qhi + ro, half, ah);
        }

#pragma unroll 1
        for (int p = 0; p < 2; ++p) {
            floatx16 acc[2];
#pragma unroll
            for (int t = 0; t < 2; ++t)
#pragma unroll
                for (int e = 0; e < 16; ++e) acc[t][e] = 0.f;

#pragma unroll
            for (int tt = 0; tt < 2; ++tt) {
                const int mr = (p * 2 + tt) * 32 + l31;
                const _Float16* rowp = Khi + (size_t)mr * 64;
#pragma unroll
                for (int ks = 0; ks < 4; ++ks) {
                    const int j = (ks * 2 + half) ^ xr;
                    halfx8 bhf = *(const halfx8*)&rowp[j << 3];
                    acc[tt] = __builtin_amdgcn_mfma_f32_32x32x16_f16(ah[ks], bhf, acc[tt], 0, 0, 0);
                }
            }

            float w0 = 0.f, w1 = 0.f;
#pragma unroll
            for (int r = 0; r < 16; ++r) {
                const int lrow = ls * 32 + rowmap(r, half);   // broadcast LDS read
                float Madj = Ms[lrow];
                w0 += fexp2(acc[0][r] - Madj);
                w1 += fexp2(acc[1][r] - Madj);
            }
            if (p == 0) { wacc0 += w0; wacc1 += w1; }
            else        { wacc2 += w0; wacc3 += w1; }
        }
    }

    // halves hold same cols, different rows: fold halves, then the 8 waves.
    float wacc[4] = {wacc0, wacc1, wacc2, wacc3};
#pragma unroll
    for (int t = 0; t < 4; ++t) wacc[t] += __shfl_xor(wacc[t], 32);
    if (half == 0) {
#pragma unroll
        for (int t = 0; t < 4; ++t) wred[wave * 128 + t * 32 + l31] = wacc[t];
    }
    __syncthreads();
    if (tid < 128) {
        float s = 0.f;
#pragma unroll
        for (int w = 0; w < 8; ++w) s += wred[w * 128 + tid];
        wfin[tid] = s;
    }
    __syncthreads();

    // Fused epilogue: out[m, :] = wfin[m - m0] * v[m, :] for m in [m0, m0+128).
    const float4* v4 = (const float4*)(v + base + (size_t)m0 * DD);
    float4* o4 = (float4*)(out + base + (size_t)m0 * DD);
#pragma unroll
    for (int i = 0; i < 4; ++i) {
        int idx = tid + 512 * i;           // 2048 float4s = 128 rows x 16
        float ww = wfin[idx >> 4];
        float4 vv = v4[idx];
        o4[idx] = make_float4(vv.x * ww, vv.y * ww, vv.z * ww, vv.w * ww);
    }
}

extern "C" void kernel_launch(void* const* d_in, const int* in_sizes, int n_in,
                              void* d_out, int out_size, void* d_ws, size_t ws_size,
                              hipStream_t stream) {
    const float* q = (const float*)d_in[0];
    const float* k = (const float*)d_in[1];
    const float* v = (const float*)d_in[2];
    float* out = (float*)d_out;

    // Workspace (~18 MB), all fully rewritten each launch:
    _Float16* qhi = (_Float16*)d_ws;
    _Float16* khi = qhi + QK;
    float* smax_p = (float*)(khi + QK);       // 2*BHNN
    float* sden_p = smax_p + 2 * BHNN;        // 2*BHNN

    convert_kernel<<<QK / 4 / 256, 256, 0, stream>>>((const float4*)q, (const float4*)k,
                                                     qhi, khi);
    stats_kernel<<<1024, 256, 0, stream>>>(qhi, khi, smax_p, sden_p);
    wsum_kernel<<<512, 512, 0, stream>>>(qhi, khi, smax_p, sden_p, v, out);
}

// Round 9
// 159.498 us; speedup vs baseline: 1.2067x; 1.0001x over previous
//
#include <hip/hip_runtime.h>
#include <math.h>

// q,k,v: [B=2, H=16, N=2048, Dh=64] fp32.  BH = 32 independent heads.
#define BH 32
#define NN 2048
#define DD 64
#define BHNN (BH * NN)        // 65536 rows total
#define QK ((size_t)BH * NN * DD)  // 4,194,304 elems per tensor

// 8 * log2(e): logits produced in base-2 domain so all softmax exps are a bare
// v_exp_f32 (exp2). Softmax is invariant to the base change.
#define QSCALE 11.5415603f

// R19: cooperative fusion (R18) failed silent-zero (launch rejected under
// graph capture / co-residency check; absmax == max|ref|). Fallback: the same
// two kernel-internal gains as ORDINARY launches (structure that passed R7):
//   - stats PAIRED: grid 512 x 512thr; waves 0-3 rows n0, waves 4-7 rows
//     n0+1024, sharing each K tile staged ONCE (staging + its bank conflicts
//     halved; one 8-wave barrier population instead of two 4-wave blocks).
//   - wsum + fused out + T14 v-prefetch: v loads issued before the reduction
//     barriers, consumed after wfin. (+16 VGPR -> ~126 <= 128 cap; WRITE_SIZE
//     is the spill canary.)
//
// R16 precision scheme (kept): SINGLE fp16 q x fp16 k MFMA per k-slice.
// absmax stayed exactly 0.25 from sigma 0.004 through 0.035 schemes: the
// 0.25 is the fp32-reference quirk, not our logit precision.
//
// Register ledger (unified VGPR+AGPR, cap 128 at 4 waves/SIMD -- spill
// history R12/R13/R15): acc[2]=32 + ah=16 + m/d or wacc + temps ~ 110.
//
// K layout (R14, kept): khi = 16KB tiles [bh][tile][128 rows][64 cols],
// intra-row swizzle: granule j at j ^ (row&7). global_load_lds stages
// LINEARLY; ds_read applies the same XOR (swizzle both sides or neither).
typedef __attribute__((ext_vector_type(8)))  _Float16 halfx8;
typedef __attribute__((ext_vector_type(4)))  _Float16 halfx4;
typedef __attribute__((ext_vector_type(16))) float    floatx16;

__device__ inline float fexp2(float x) { return __builtin_amdgcn_exp2f(x); }
__device__ inline float flog2(float x) { return __builtin_amdgcn_logf(x); }

// C/D row for accumulator register r (0..15) given half = lane>>5 (verified R2).
__device__ inline int rowmap(int r, int half) {
    return (r & 3) + 8 * (r >> 2) + 4 * half;
}

// ---------------------------------------------------------------------------
// Pre-convert: q -> fp16 (QSCALE folded), k -> fp16, k swizzled.
// ---------------------------------------------------------------------------
__global__ __launch_bounds__(256) void convert_kernel(const float4* __restrict__ q,
                                                      const float4* __restrict__ k,
                                                      _Float16* __restrict__ qhi,
                                                      _Float16* __restrict__ khi) {
    size_t gid = (size_t)blockIdx.x * 256 + threadIdx.x;  // float4 index, QK/4 total
    float4 qa = q[gid];
    float4 ka = k[gid];
    float qf[4] = {qa.x, qa.y, qa.z, qa.w};
    float kf[4] = {ka.x, ka.y, ka.z, ka.w};
    halfx4 h, kh;
#pragma unroll
    for (int i = 0; i < 4; ++i) {
        h[i]  = (_Float16)(qf[i] * QSCALE);  // RN
        kh[i] = (_Float16)kf[i];
    }
    *(halfx4*)&qhi[gid * 4] = h;
    // swizzled K: row = (gid>>4)&127; granule j = (gid>>1)&7; sub = (gid&1)*4
    size_t rowbase = (gid * 4) & ~(size_t)63;
    int j = (int)((gid >> 1) & 7) ^ (int)((gid >> 4) & 7);
    *(halfx4*)&khi[rowbase + (size_t)(j << 3) + ((gid & 1) << 2)] = kh;
}

// ---------------------------------------------------------------------------
// Async stage: one 16KB K-tile image -> LDS via 8 waves, linear copy.
// LDS dest = wave-uniform base + lane*16 (HW rule); global src per-lane.
// Tracked by vmcnt; __syncthreads() drains it.
// ---------------------------------------------------------------------------
__device__ inline void stage_tile_async8(const _Float16* __restrict__ gtile,
                                         _Float16* lds, int wave, int lane) {
#pragma unroll
    for (int i = 0; i < 2; ++i) {
        const char* gp = (const char*)gtile + wave * 2048 + i * 1024 + lane * 16;
        char* lp = (char*)lds + wave * 2048 + i * 1024;   // wave-uniform
        __builtin_amdgcn_global_load_lds(
            (const __attribute__((address_space(1))) unsigned int*)gp,
            (__attribute__((address_space(3))) unsigned int*)lp, 16, 0, 0);
    }
}

// ---- A-operand fragments: lane holds A[m=lane&31][k=(lane>>5)*8+j] ----------
__device__ inline void load_a(const _Float16* __restrict__ qhi_row,
                              int half, halfx8 ah[4]) {
#pragma unroll
    for (int ks = 0; ks < 4; ++ks)
        ah[ks] = *(const halfx8*)&qhi_row[ks * 16 + half * 8];
}

// ---------------------------------------------------------------------------
// Phase 1 (R19 paired): per-row softmax stats (base-2), PARTIAL over an
// m-half.  Grid 512 x 512thr: block b -> (bh, ms) = (b&31, (b>>5)&1),
// n0 = (b>>6)*128.  Waves 0-3 take rows n0+.., waves 4-7 take n0+1024+..,
// sharing each K tile staged ONCE.  Blocks with the same (bh,ms) are
// congruent mod 64 => same XCD (shared K-half L2 locality).
// acc[2] x 2 passes (unroll 1) under __launch_bounds__(512,4).
// ---------------------------------------------------------------------------
__global__ __launch_bounds__(512, 4) void stats_kernel(const _Float16* __restrict__ qhi,
                                                       const _Float16* __restrict__ khi,
                                                       float* __restrict__ smax_p,
                                                       float* __restrict__ sden_p) {
    __shared__ _Float16 K2[2 * 128 * 64];  // 32 KB, two tile buffers
    const int b    = blockIdx.x;
    const int g    = b & 63;               // bh + 32*ms
    const int bh   = g & 31;
    const int ms   = g >> 5;               // m-split: tiles [ms*8, ms*8+8)
    const int n0   = (b >> 6) * 128;
    const int tid  = threadIdx.x;
    const int wave = tid >> 6, lane = tid & 63;
    const int half = lane >> 5, l31 = lane & 31;
    const int xr   = l31 & 7;              // row&7 for swizzled reads
    const int sub  = wave >> 2, w4 = wave & 3;
    const size_t base = (size_t)bh * NN * DD;

    const _Float16* khi_b = khi + base;
    stage_tile_async8(khi_b + (size_t)(ms * 8) * 8192, K2, wave, lane);

    // A fragments: fixed rows for the whole kernel.
    halfx8 ah[4];
    {
        size_t ro = base + (size_t)(n0 + sub * 1024 + w4 * 32 + l31) * DD;
        load_a(qhi + ro, half, ah);
    }

    float m_run[16], d_run[16];
#pragma unroll
    for (int r = 0; r < 16; ++r) { m_run[r] = -INFINITY; d_run[r] = 0.f; }

    __syncthreads();                       // tile 0 landed (vmcnt drain) + barrier

#pragma unroll 1
    for (int mti = 0; mti < 8; ++mti) {
        const _Float16* Kc = K2 + (mti & 1) * 8192;
        if (mti < 7)                       // issue next tile BEFORE compute
            stage_tile_async8(khi_b + (size_t)(ms * 8 + mti + 1) * 8192,
                              K2 + ((mti + 1) & 1) * 8192, wave, lane);

#pragma unroll 1
        for (int p = 0; p < 2; ++p) {      // two half-width passes: t = 2p+tt
            floatx16 acc[2];
#pragma unroll
            for (int t = 0; t < 2; ++t)
#pragma unroll
                for (int e = 0; e < 16; ++e) acc[t][e] = 0.f;

#pragma unroll
            for (int tt = 0; tt < 2; ++tt) {
                const int mr = (p * 2 + tt) * 32 + l31;
                const _Float16* rowp = Kc + (size_t)mr * 64;
#pragma unroll
                for (int ks = 0; ks < 4; ++ks) {
                    const int j = (ks * 2 + half) ^ xr;
                    halfx8 bhf = *(const halfx8*)&rowp[j << 3];
                    acc[tt] = __builtin_amdgcn_mfma_f32_32x32x16_f16(ah[ks], bhf, acc[tt], 0, 0, 0);
                }
            }

            // Lazy per-lane online stats, base-2 domain.
#pragma unroll
            for (int r = 0; r < 16; ++r) {
                float tmax = fmaxf(acc[0][r], acc[1][r]);
                float m_new = fmaxf(m_run[r], tmax);
                float s = fexp2(acc[0][r] - m_new) + fexp2(acc[1][r] - m_new);
                d_run[r] = d_run[r] * fexp2(m_run[r] - m_new) + s;
                m_run[r] = m_new;
            }
        }

        if (mti < 7) __syncthreads();      // t+1 loads landed + all waves done with Kc
    }

    // Cross-lane combine within each 32-lane half (rows differ across halves).
    float* smp = smax_p + ((size_t)ms * BH + bh) * NN;
    float* sdp = sden_p + ((size_t)ms * BH + bh) * NN;
#pragma unroll
    for (int r = 0; r < 16; ++r) {
        float M = m_run[r];
#pragma unroll
        for (int off = 1; off < 32; off <<= 1)
            M = fmaxf(M, __shfl_xor(M, off));
        float dd = d_run[r] * fexp2(m_run[r] - M);
#pragma unroll
        for (int off = 1; off < 32; off <<= 1)
            dd += __shfl_xor(dd, off);
        if (l31 == 0) {
            int row = n0 + sub * 1024 + w4 * 32 + rowmap(r, half);
            smp[row] = M;
            sdp[row] = dd;
        }
    }
}

// ---------------------------------------------------------------------------
// Phase 2 (R17 + T14): w[m] over ALL rows + fused output.  Grid 512 =
// bh + 32*m0i, 512 threads (8 waves).  Block owns 128 cols; K tile staged
// once; waves stride 64 row-strips of 32.  Per-row Madj = M + log2(den)
// staged in LDS.  v-prefetch: epilogue's v reads issued before the
// reduction barriers, consumed after wfin.
// ---------------------------------------------------------------------------
__global__ __launch_bounds__(512, 4) void wsum_kernel(const _Float16* __restrict__ qhi,
                                                      const _Float16* __restrict__ khi,
                                                      const float* __restrict__ smax_p,
                                                      const float* __restrict__ sden_p,
                                                      const float* __restrict__ v,
                                                      float* __restrict__ out) {
    __shared__ _Float16 Khi[128 * 64];     // 16 KB, single tile
    __shared__ float Ms[2048];             // 8 KB: Madj for all rows of bh
    __shared__ float wred[8 * 128];        // 4 KB
    __shared__ float wfin[128];
    const int b    = blockIdx.x;
    const int bh   = b & 31;
    const int m0   = (b >> 5) * 128;       // col block
    const int tid  = threadIdx.x;
    const int wave = tid >> 6, lane = tid & 63;
    const int half = lane >> 5, l31 = lane & 31;
    const int xr   = l31 & 7;
    const size_t base = (size_t)bh * NN * DD;

    stage_tile_async8(khi + base + (size_t)m0 * 64, Khi, wave, lane);

    {   // combine row stats inline (4 rows/thread) while the tile streams in
        size_t roff = (size_t)bh * NN + tid * 4;
        float4 m0v = *(const float4*)&smax_p[roff];
        float4 m1v = *(const float4*)&smax_p[(size_t)BHNN + roff];
        float4 d0v = *(const float4*)&sden_p[roff];
        float4 d1v = *(const float4*)&sden_p[(size_t)BHNN + roff];
        float mm0[4] = {m0v.x, m0v.y, m0v.z, m0v.w};
        float mm1[4] = {m1v.x, m1v.y, m1v.z, m1v.w};
        float dd0[4] = {d0v.x, d0v.y, d0v.z, d0v.w};
        float dd1[4] = {d1v.x, d1v.y, d1v.z, d1v.w};
#pragma unroll
        for (int j = 0; j < 4; ++j) {
            float M = fmaxf(mm0[j], mm1[j]);
            float den = dd0[j] * fexp2(mm0[j] - M) + dd1[j] * fexp2(mm1[j] - M);
            Ms[tid * 4 + j] = M + flog2(den);
        }
    }
    __syncthreads();                       // K tile landed + Ms visible

    float wacc0 = 0.f, wacc1 = 0.f, wacc2 = 0.f, wacc3 = 0.f;

#pragma unroll 1
    for (int it = 0; it < 8; ++it) {
        const int ls = wave + it * 8;      // local strip 0..63 (32 rows each)
        halfx8 ah[4];
        {
            size_t ro = base + (size_t)(ls * 32 + l31) * DD;
            load_a(qhi + ro, half, ah);
        }

#pragma unroll 1
        for (int p = 0; p < 2; ++p) {
            floatx16 acc[2];
#pragma unroll
            for (int t = 0; t < 2; ++t)
#pragma unroll
                for (int e = 0; e < 16; ++e) acc[t][e] = 0.f;

#pragma unroll
            for (int tt = 0; tt < 2; ++tt) {
                const int mr = (p * 2 + tt) * 32 + l31;
                const _Float16* rowp = Khi + (size_t)mr * 64;
#pragma unroll
                for (int ks = 0; ks < 4; ++ks) {
                    const int j = (ks * 2 + half) ^ xr;
                    halfx8 bhf = *(const halfx8*)&rowp[j << 3];
                    acc[tt] = __builtin_amdgcn_mfma_f32_32x32x16_f16(ah[ks], bhf, acc[tt], 0, 0, 0);
                }
            }

            float w0 = 0.f, w1 = 0.f;
#pragma unroll
            for (int r = 0; r < 16; ++r) {
                const int lrow = ls * 32 + rowmap(r, half);   // broadcast LDS read
                float Madj = Ms[lrow];
                w0 += fexp2(acc[0][r] - Madj);
                w1 += fexp2(acc[1][r] - Madj);
            }
            if (p == 0) { wacc0 += w0; wacc1 += w1; }
            else        { wacc2 += w0; wacc3 += w1; }
        }
    }

    // T14 v-prefetch: issue the epilogue's v reads now; they land under the
    // reduction barriers below.
    const float4* v4 = (const float4*)(v + base + (size_t)m0 * DD);
    float4 vpre[4];
#pragma unroll
    for (int i = 0; i < 4; ++i) vpre[i] = v4[tid + 512 * i];

    // halves hold same cols, different rows: fold halves, then the 8 waves.
    float wacc[4] = {wacc0, wacc1, wacc2, wacc3};
#pragma unroll
    for (int t = 0; t < 4; ++t) wacc[t] += __shfl_xor(wacc[t], 32);
    if (half == 0) {
#pragma unroll
        for (int t = 0; t < 4; ++t) wred[wave * 128 + t * 32 + l31] = wacc[t];
    }
    __syncthreads();
    if (tid < 128) {
        float s = 0.f;
#pragma unroll
        for (int w = 0; w < 8; ++w) s += wred[w * 128 + tid];
        wfin[tid] = s;
    }
    __syncthreads();

    // Fused epilogue: out[m, :] = wfin[m - m0] * v[m, :] for m in [m0, m0+128).
    float4* o4 = (float4*)(out + base + (size_t)m0 * DD);
#pragma unroll
    for (int i = 0; i < 4; ++i) {
        int idx = tid + 512 * i;           // 2048 float4s = 128 rows x 16
        float ww = wfin[idx >> 4];
        o4[idx] = make_float4(vpre[i].x * ww, vpre[i].y * ww,
                              vpre[i].z * ww, vpre[i].w * ww);
    }
}

extern "C" void kernel_launch(void* const* d_in, const int* in_sizes, int n_in,
                              void* d_out, int out_size, void* d_ws, size_t ws_size,
                              hipStream_t stream) {
    const float* q = (const float*)d_in[0];
    const float* k = (const float*)d_in[1];
    const float* v = (const float*)d_in[2];
    float* out = (float*)d_out;

    // Workspace (~17 MB), all fully rewritten each launch:
    _Float16* qhi = (_Float16*)d_ws;
    _Float16* khi = qhi + QK;
    float* smax_p = (float*)(khi + QK);       // 2*BHNN
    float* sden_p = smax_p + 2 * BHNN;        // 2*BHNN

    convert_kernel<<<QK / 4 / 256, 256, 0, stream>>>((const float4*)q, (const float4*)k,
                                                     qhi, khi);
    stats_kernel<<<512, 512, 0, stream>>>(qhi, khi, smax_p, sden_p);
    wsum_kernel<<<512, 512, 0, stream>>>(qhi, khi, smax_p, sden_p, v, out);
}

// Round 10
// 155.500 us; speedup vs baseline: 1.2377x; 1.0257x over previous
//
#include <hip/hip_runtime.h>
#include <math.h>

// q,k,v: [B=2, H=16, N=2048, Dh=64] fp32.  BH = 32 independent heads.
#define BH 32
#define NN 2048
#define DD 64
#define BHNN (BH * NN)        // 65536 rows total
#define QK ((size_t)BH * NN * DD)  // 4,194,304 elems per tensor

// 8 * log2(e): logits produced in base-2 domain so all softmax exps are a bare
// v_exp_f32 (exp2). Softmax is invariant to the base change.
#define QSCALE 11.5415603f

// R20 consolidation:
//   - stats: EXACT R6 shape (grid 1024 x 256thr, (256,4), async4 staging,
//     acc[2] x 2 passes) -- measured 46.9us / WRITE 4MB. R9's pairing
//     regressed it (51.0us, WRITE 9.2MB: +8 regs of spill) -- reverted.
//   - wsum: R9 shape (512 x 512thr, fused out + T14 v-prefetch, ~48us) plus
//     Madj folded into the MFMA accumulator init: Ms holds -(M + log2 den),
//     acc init = Ms[row] so the MFMA C-input does the subtraction exactly;
//     r-loop is w += exp2(acc[r]) -- removes 512 subs + 256 broadcast reads
//     per wave.
//
// R16 precision scheme (kept): SINGLE fp16 q x fp16 k MFMA per k-slice.
// absmax stayed exactly 0.25 from sigma 0.004 through 0.035 schemes: the
// 0.25 is the fp32-reference quirk, not our logit precision.
//
// Register ledger (unified VGPR+AGPR, cap 128 at 4 waves/SIMD; spill history
// R12/R13/R15/R19): every add-on costs spill before it pays. acc[2]=32 +
// ah=16 + m/d or wacc + temps ~ 110 <= 128.
//
// K layout (R14, kept): khi = 16KB tiles [bh][tile][128 rows][64 cols],
// intra-row swizzle: granule j at j ^ (row&7). global_load_lds stages
// LINEARLY; ds_read applies the same XOR (swizzle both sides or neither).
typedef __attribute__((ext_vector_type(8)))  _Float16 halfx8;
typedef __attribute__((ext_vector_type(4)))  _Float16 halfx4;
typedef __attribute__((ext_vector_type(16))) float    floatx16;

__device__ inline float fexp2(float x) { return __builtin_amdgcn_exp2f(x); }
__device__ inline float flog2(float x) { return __builtin_amdgcn_logf(x); }

// C/D row for accumulator register r (0..15) given half = lane>>5 (verified R2).
__device__ inline int rowmap(int r, int half) {
    return (r & 3) + 8 * (r >> 2) + 4 * half;
}

// ---------------------------------------------------------------------------
// Pre-convert: q -> fp16 (QSCALE folded), k -> fp16, k swizzled.
// ---------------------------------------------------------------------------
__global__ __launch_bounds__(256) void convert_kernel(const float4* __restrict__ q,
                                                      const float4* __restrict__ k,
                                                      _Float16* __restrict__ qhi,
                                                      _Float16* __restrict__ khi) {
    size_t gid = (size_t)blockIdx.x * 256 + threadIdx.x;  // float4 index, QK/4 total
    float4 qa = q[gid];
    float4 ka = k[gid];
    float qf[4] = {qa.x, qa.y, qa.z, qa.w};
    float kf[4] = {ka.x, ka.y, ka.z, ka.w};
    halfx4 h, kh;
#pragma unroll
    for (int i = 0; i < 4; ++i) {
        h[i]  = (_Float16)(qf[i] * QSCALE);  // RN
        kh[i] = (_Float16)kf[i];
    }
    *(halfx4*)&qhi[gid * 4] = h;
    // swizzled K: row = (gid>>4)&127; granule j = (gid>>1)&7; sub = (gid&1)*4
    size_t rowbase = (gid * 4) & ~(size_t)63;
    int j = (int)((gid >> 1) & 7) ^ (int)((gid >> 4) & 7);
    *(halfx4*)&khi[rowbase + (size_t)(j << 3) + ((gid & 1) << 2)] = kh;
}

// ---------------------------------------------------------------------------
// Async stage: one 16KB K-tile image -> LDS, linear copy, no VGPR round-trip.
// LDS dest = wave-uniform base + lane*16 (HW rule); global src per-lane.
// Tracked by vmcnt; __syncthreads() drains it.  4-wave and 8-wave variants.
// ---------------------------------------------------------------------------
__device__ inline void stage_tile_async4(const _Float16* __restrict__ gtile,
                                         _Float16* lds, int wave, int lane) {
#pragma unroll
    for (int i = 0; i < 4; ++i) {
        const char* gp = (const char*)gtile + wave * 4096 + i * 1024 + lane * 16;
        char* lp = (char*)lds + wave * 4096 + i * 1024;   // wave-uniform
        __builtin_amdgcn_global_load_lds(
            (const __attribute__((address_space(1))) unsigned int*)gp,
            (__attribute__((address_space(3))) unsigned int*)lp, 16, 0, 0);
    }
}
__device__ inline void stage_tile_async8(const _Float16* __restrict__ gtile,
                                         _Float16* lds, int wave, int lane) {
#pragma unroll
    for (int i = 0; i < 2; ++i) {
        const char* gp = (const char*)gtile + wave * 2048 + i * 1024 + lane * 16;
        char* lp = (char*)lds + wave * 2048 + i * 1024;   // wave-uniform
        __builtin_amdgcn_global_load_lds(
            (const __attribute__((address_space(1))) unsigned int*)gp,
            (__attribute__((address_space(3))) unsigned int*)lp, 16, 0, 0);
    }
}

// ---- A-operand fragments: lane holds A[m=lane&31][k=(lane>>5)*8+j] ----------
__device__ inline void load_a(const _Float16* __restrict__ qhi_row,
                              int half, halfx8 ah[4]) {
#pragma unroll
    for (int ks = 0; ks < 4; ++ks)
        ah[ks] = *(const halfx8*)&qhi_row[ks * 16 + half * 8];
}

// ---------------------------------------------------------------------------
// Phase 1: per-row softmax stats (base-2), PARTIAL over an m-half.
// EXACT R6 shape (measured 46.9us): 1D grid 1024: idx = (bh + 32*ms) +
// 64*nblk -> blocks sharing a K-half are congruent mod 8 => same XCD.
// acc[2] x 2 passes (unroll 1) under __launch_bounds__(256,4).
// ---------------------------------------------------------------------------
__global__ __launch_bounds__(256, 4) void stats_kernel(const _Float16* __restrict__ qhi,
                                                       const _Float16* __restrict__ khi,
                                                       float* __restrict__ smax_p,
                                                       float* __restrict__ sden_p) {
    __shared__ _Float16 K2[2 * 128 * 64];  // 32 KB, two tile buffers
    const int g    = blockIdx.x & 63;      // bh + 32*ms
    const int bh   = g & 31;
    const int ms   = g >> 5;               // m-split: tiles [ms*8, ms*8+8)
    const int n0   = (blockIdx.x >> 6) * 128;
    const int tid  = threadIdx.x;
    const int wave = tid >> 6, lane = tid & 63;
    const int half = lane >> 5, l31 = lane & 31;
    const int xr   = l31 & 7;              // row&7 for swizzled reads
    const size_t base = (size_t)bh * NN * DD;

    const _Float16* khi_b = khi + base;
    stage_tile_async4(khi_b + (size_t)(ms * 8) * 8192, K2, wave, lane);

    // A fragments: fixed rows for the whole kernel.
    halfx8 ah[4];
    {
        size_t ro = base + (size_t)(n0 + wave * 32 + l31) * DD;
        load_a(qhi + ro, half, ah);
    }

    float m_run[16], d_run[16];
#pragma unroll
    for (int r = 0; r < 16; ++r) { m_run[r] = -INFINITY; d_run[r] = 0.f; }

    __syncthreads();                       // tile 0 landed (vmcnt drain) + barrier

#pragma unroll 1
    for (int mti = 0; mti < 8; ++mti) {
        const _Float16* Kc = K2 + (mti & 1) * 8192;
        if (mti < 7)                       // issue next tile BEFORE compute
            stage_tile_async4(khi_b + (size_t)(ms * 8 + mti + 1) * 8192,
                              K2 + ((mti + 1) & 1) * 8192, wave, lane);

#pragma unroll 1
        for (int p = 0; p < 2; ++p) {      // two half-width passes: t = 2p+tt
            floatx16 acc[2];
#pragma unroll
            for (int t = 0; t < 2; ++t)
#pragma unroll
                for (int e = 0; e < 16; ++e) acc[t][e] = 0.f;

#pragma unroll
            for (int tt = 0; tt < 2; ++tt) {
                const int mr = (p * 2 + tt) * 32 + l31;
                const _Float16* rowp = Kc + (size_t)mr * 64;
#pragma unroll
                for (int ks = 0; ks < 4; ++ks) {
                    const int j = (ks * 2 + half) ^ xr;
                    halfx8 bhf = *(const halfx8*)&rowp[j << 3];
                    acc[tt] = __builtin_amdgcn_mfma_f32_32x32x16_f16(ah[ks], bhf, acc[tt], 0, 0, 0);
                }
            }

            // Lazy per-lane online stats, base-2 domain.
#pragma unroll
            for (int r = 0; r < 16; ++r) {
                float tmax = fmaxf(acc[0][r], acc[1][r]);
                float m_new = fmaxf(m_run[r], tmax);
                float s = fexp2(acc[0][r] - m_new) + fexp2(acc[1][r] - m_new);
                d_run[r] = d_run[r] * fexp2(m_run[r] - m_new) + s;
                m_run[r] = m_new;
            }
        }

        if (mti < 7) __syncthreads();      // t+1 loads landed + all waves done with Kc
    }

    // Cross-lane combine within each 32-lane half (rows differ across halves).
    float* smp = smax_p + ((size_t)ms * BH + bh) * NN;
    float* sdp = sden_p + ((size_t)ms * BH + bh) * NN;
#pragma unroll
    for (int r = 0; r < 16; ++r) {
        float M = m_run[r];
#pragma unroll
        for (int off = 1; off < 32; off <<= 1)
            M = fmaxf(M, __shfl_xor(M, off));
        float dd = d_run[r] * fexp2(m_run[r] - M);
#pragma unroll
        for (int off = 1; off < 32; off <<= 1)
            dd += __shfl_xor(dd, off);
        if (l31 == 0) {
            int row = n0 + wave * 32 + rowmap(r, half);
            smp[row] = M;
            sdp[row] = dd;
        }
    }
}

// ---------------------------------------------------------------------------
// Phase 2 (R20): w[m] over ALL rows + fused output.  Grid 512 = bh + 32*m0i,
// 512 threads (8 waves).  Block owns 128 cols; K tile staged once; waves
// stride 64 row-strips of 32.  Ms holds NEGATED Madj = -(M + log2 den);
// the MFMA accumulator is INITIALIZED with it, so the C-input performs the
// subtraction exactly and the r-loop is a bare exp2 + add.
// T14 v-prefetch: epilogue's v reads issued before the reduction barriers.
// ---------------------------------------------------------------------------
__global__ __launch_bounds__(512, 4) void wsum_kernel(const _Float16* __restrict__ qhi,
                                                      const _Float16* __restrict__ khi,
                                                      const float* __restrict__ smax_p,
                                                      const float* __restrict__ sden_p,
                                                      const float* __restrict__ v,
                                                      float* __restrict__ out) {
    __shared__ _Float16 Khi[128 * 64];     // 16 KB, single tile
    __shared__ float Ms[2048];             // 8 KB: -(M + log2 den) for all rows
    __shared__ float wred[8 * 128];        // 4 KB
    __shared__ float wfin[128];
    const int b    = blockIdx.x;
    const int bh   = b & 31;
    const int m0   = (b >> 5) * 128;       // col block
    const int tid  = threadIdx.x;
    const int wave = tid >> 6, lane = tid & 63;
    const int half = lane >> 5, l31 = lane & 31;
    const int xr   = l31 & 7;
    const size_t base = (size_t)bh * NN * DD;

    stage_tile_async8(khi + base + (size_t)m0 * 64, Khi, wave, lane);

    {   // combine row stats inline (4 rows/thread) while the tile streams in
        size_t roff = (size_t)bh * NN + tid * 4;
        float4 m0v = *(const float4*)&smax_p[roff];
        float4 m1v = *(const float4*)&smax_p[(size_t)BHNN + roff];
        float4 d0v = *(const float4*)&sden_p[roff];
        float4 d1v = *(const float4*)&sden_p[(size_t)BHNN + roff];
        float mm0[4] = {m0v.x, m0v.y, m0v.z, m0v.w};
        float mm1[4] = {m1v.x, m1v.y, m1v.z, m1v.w};
        float dd0[4] = {d0v.x, d0v.y, d0v.z, d0v.w};
        float dd1[4] = {d1v.x, d1v.y, d1v.z, d1v.w};
#pragma unroll
        for (int j = 0; j < 4; ++j) {
            float M = fmaxf(mm0[j], mm1[j]);
            float den = dd0[j] * fexp2(mm0[j] - M) + dd1[j] * fexp2(mm1[j] - M);
            Ms[tid * 4 + j] = -(M + flog2(den));   // negated Madj
        }
    }
    __syncthreads();                       // K tile landed + Ms visible

    float wacc0 = 0.f, wacc1 = 0.f, wacc2 = 0.f, wacc3 = 0.f;

#pragma unroll 1
    for (int it = 0; it < 8; ++it) {
        const int ls = wave + it * 8;      // local strip 0..63 (32 rows each)
        halfx8 ah[4];
        {
            size_t ro = base + (size_t)(ls * 32 + l31) * DD;
            load_a(qhi + ro, half, ah);
        }

#pragma unroll 1
        for (int p = 0; p < 2; ++p) {
            floatx16 acc[2];
#pragma unroll
            for (int e = 0; e < 16; ++e) {
                float mb = Ms[ls * 32 + rowmap(e, half)];  // broadcast LDS read
                acc[0][e] = mb;
                acc[1][e] = mb;
            }

#pragma unroll
            for (int tt = 0; tt < 2; ++tt) {
                const int mr = (p * 2 + tt) * 32 + l31;
                const _Float16* rowp = Khi + (size_t)mr * 64;
#pragma unroll
                for (int ks = 0; ks < 4; ++ks) {
                    const int j = (ks * 2 + half) ^ xr;
                    halfx8 bhf = *(const halfx8*)&rowp[j << 3];
                    acc[tt] = __builtin_amdgcn_mfma_f32_32x32x16_f16(ah[ks], bhf, acc[tt], 0, 0, 0);
                }
            }

            float w0 = 0.f, w1 = 0.f;
#pragma unroll
            for (int r = 0; r < 16; ++r) {
                w0 += fexp2(acc[0][r]);
                w1 += fexp2(acc[1][r]);
            }
            if (p == 0) { wacc0 += w0; wacc1 += w1; }
            else        { wacc2 += w0; wacc3 += w1; }
        }
    }

    // T14 v-prefetch: issue the epilogue's v reads now; they land under the
    // reduction barriers below.
    const float4* v4 = (const float4*)(v + base + (size_t)m0 * DD);
    float4 vpre[4];
#pragma unroll
    for (int i = 0; i < 4; ++i) vpre[i] = v4[tid + 512 * i];

    // halves hold same cols, different rows: fold halves, then the 8 waves.
    float wacc[4] = {wacc0, wacc1, wacc2, wacc3};
#pragma unroll
    for (int t = 0; t < 4; ++t) wacc[t] += __shfl_xor(wacc[t], 32);
    if (half == 0) {
#pragma unroll
        for (int t = 0; t < 4; ++t) wred[wave * 128 + t * 32 + l31] = wacc[t];
    }
    __syncthreads();
    if (tid < 128) {
        float s = 0.f;
#pragma unroll
        for (int w = 0; w < 8; ++w) s += wred[w * 128 + tid];
        wfin[tid] = s;
    }
    __syncthreads();

    // Fused epilogue: out[m, :] = wfin[m - m0] * v[m, :] for m in [m0, m0+128).
    float4* o4 = (float4*)(out + base + (size_t)m0 * DD);
#pragma unroll
    for (int i = 0; i < 4; ++i) {
        int idx = tid + 512 * i;           // 2048 float4s = 128 rows x 16
        float ww = wfin[idx >> 4];
        o4[idx] = make_float4(vpre[i].x * ww, vpre[i].y * ww,
                              vpre[i].z * ww, vpre[i].w * ww);
    }
}

extern "C" void kernel_launch(void* const* d_in, const int* in_sizes, int n_in,
                              void* d_out, int out_size, void* d_ws, size_t ws_size,
                              hipStream_t stream) {
    const float* q = (const float*)d_in[0];
    const float* k = (const float*)d_in[1];
    const float* v = (const float*)d_in[2];
    float* out = (float*)d_out;

    // Workspace (~17 MB), all fully rewritten each launch:
    _Float16* qhi = (_Float16*)d_ws;
    _Float16* khi = qhi + QK;
    float* smax_p = (float*)(khi + QK);       // 2*BHNN
    float* sden_p = smax_p + 2 * BHNN;        // 2*BHNN

    convert_kernel<<<QK / 4 / 256, 256, 0, stream>>>((const float4*)q, (const float4*)k,
                                                     qhi, khi);
    stats_kernel<<<1024, 256, 0, stream>>>(qhi, khi, smax_p, sden_p);
    wsum_kernel<<<512, 512, 0, stream>>>(qhi, khi, smax_p, sden_p, v, out);
}